// Round 1
// baseline (962.190 us; speedup 1.0000x reference)
//
#include <hip/hip_runtime.h>

// ---------------- constants (problem-fixed sizes) ----------------
#define N_NODES 20000
#define M_PAD   20096   // 157 * 128
#define E_EDGES 320000

typedef unsigned short u16;
typedef unsigned int   u32;
typedef __attribute__((ext_vector_type(8))) short bf16x8;
typedef __attribute__((ext_vector_type(4))) float f32x4;

__device__ __forceinline__ float bf2f(u16 u){
  u32 x = ((u32)u) << 16; float f; __builtin_memcpy(&f, &x, 4); return f;
}
__device__ __forceinline__ u16 f2bf(float f){
  u32 u; __builtin_memcpy(&u, &f, 4);
  u += 0x7fffu + ((u >> 16) & 1u);          // RNE
  return (u16)(u >> 16);
}

__device__ __forceinline__ void gl_lds16(const void* g, void* l){
  __builtin_amdgcn_global_load_lds((const __attribute__((address_space(1))) void*)g,
                                   (__attribute__((address_space(3))) void*)l, 16, 0, 0);
}

// ---------------- CSR build ----------------
__global__ void hist_k(const int* __restrict__ ei, int* __restrict__ cnt){
  int i = blockIdx.x * 256 + threadIdx.x;
  if (i < E_EDGES) atomicAdd(&cnt[ei[E_EDGES + i]], 1);
}

__global__ void scan_k(const int* __restrict__ cnt, int* __restrict__ rowp, int n){
  __shared__ int buf[1024]; __shared__ int carry;
  int tid = threadIdx.x;
  if (tid == 0) carry = 0;
  __syncthreads();
  for (int base = 0; base < n; base += 1024){
    int i = base + tid;
    int v = (i < n) ? cnt[i] : 0;
    buf[tid] = v; __syncthreads();
    for (int off = 1; off < 1024; off <<= 1){
      int t = (tid >= off) ? buf[tid - off] : 0; __syncthreads();
      buf[tid] += t; __syncthreads();
    }
    int incl = buf[tid];
    int c0 = carry;
    __syncthreads();
    if (i < n) rowp[i] = c0 + incl - v;     // exclusive prefix
    if (tid == 1023) carry = c0 + incl;
    __syncthreads();
  }
  if (tid == 0) rowp[n] = carry;
}

__global__ void copy_int_k(const int* __restrict__ a, int* __restrict__ b, int n){
  int i = blockIdx.x * 256 + threadIdx.x; if (i < n) b[i] = a[i];
}

__global__ void scatter_k(const int* __restrict__ ei, int* __restrict__ fill, int* __restrict__ esrc){
  int i = blockIdx.x * 256 + threadIdx.x;
  if (i < E_EDGES){
    int d = ei[E_EDGES + i];
    int p = atomicAdd(&fill[d], 1);
    esrc[p] = ei[i];
  }
}

// ---------------- casts / transposes ----------------
// src fp32 [K][Nc] -> dst bf16 rows [n0+n][k], row stride ldd (=K)
__global__ void tcast_k(const float* __restrict__ src, int Nc, u16* __restrict__ dst, int n0, int ldd){
  __shared__ float tile[32][33];
  int kb = blockIdx.y * 32, nb = blockIdx.x * 32;
  int tx = threadIdx.x, ty = threadIdx.y;
#pragma unroll
  for (int r = 0; r < 32; r += 8)
    tile[ty + r][tx] = src[(size_t)(kb + ty + r) * Nc + nb + tx];
  __syncthreads();
#pragma unroll
  for (int r = 0; r < 32; r += 8){
    int n = nb + ty + r;
    dst[(size_t)(n0 + n) * ldd + kb + tx] = f2bf(tile[tx][ty + r]);
  }
}

__global__ void castx_k(const float* __restrict__ x, u16* __restrict__ o, int realRows, int cols){
  int r = blockIdx.y, c = blockIdx.x * 256 + threadIdx.x;
  float v = (r < realRows) ? x[(size_t)r * cols + c] : 0.f;
  o[(size_t)r * cols + c] = f2bf(v);
}

__global__ void zpad_k(u16* __restrict__ p, int n){
  int i = blockIdx.x * 256 + threadIdx.x; if (i < n) p[i] = 0;
}

// ---------------- bf16 NT GEMM: C[M][N] = A[M][K] * Bt[N][K]^T ----------------
// 128x128 tile, BK=32, 256 threads (4 waves, each 64x64 = 4x4 MFMA 16x16x32)
__global__ __launch_bounds__(256)
void gemm_bf16(const u16* __restrict__ A, const u16* __restrict__ Bt, u16* __restrict__ C,
               int N, int K)
{
  __shared__ __attribute__((aligned(16))) u16 lA[128 * 32];
  __shared__ __attribute__((aligned(16))) u16 lB[128 * 32];
  const int tid  = threadIdx.x;
  const int wave = tid >> 6, lane = tid & 63;
  const int bm = blockIdx.x, bn = blockIdx.y;
  const int wm = (wave >> 1) * 64, wn = (wave & 1) * 64;

  // staging mapping: per wave-instruction, 16 rows x 32 k (lane -> row lane/4, k (lane%4)*8)
  const int srow  = wave * 16 + (lane >> 2);
  const int skcol = (lane & 3) * 8;
  const u16* Ag0 = A  + (size_t)(bm * 128 + srow) * K + skcol;
  const u16* Ag1 = Ag0 + (size_t)64 * K;
  const u16* Bg0 = Bt + (size_t)(bn * 128 + srow) * K + skcol;
  const u16* Bg1 = Bg0 + (size_t)64 * K;
  u16* lA0 = lA + wave * 512; u16* lA1 = lA + 2048 + wave * 512;
  u16* lB0 = lB + wave * 512; u16* lB1 = lB + 2048 + wave * 512;

  f32x4 acc[4][4] = {};

  for (int k0 = 0; k0 < K; k0 += 32){
    gl_lds16(Ag0 + k0, lA0);
    gl_lds16(Ag1 + k0, lA1);
    gl_lds16(Bg0 + k0, lB0);
    gl_lds16(Bg1 + k0, lB1);
    __syncthreads();                      // drain vmcnt -> LDS tiles ready
    const int koff = (lane >> 4) * 8;
    const int rsel = lane & 15;
    bf16x8 af[4], bfr[4];
#pragma unroll
    for (int i = 0; i < 4; i++) af[i]  = *(const bf16x8*)&lA[(wm + i * 16 + rsel) * 32 + koff];
#pragma unroll
    for (int j = 0; j < 4; j++) bfr[j] = *(const bf16x8*)&lB[(wn + j * 16 + rsel) * 32 + koff];
#pragma unroll
    for (int i = 0; i < 4; i++)
#pragma unroll
      for (int j = 0; j < 4; j++)
        acc[i][j] = __builtin_amdgcn_mfma_f32_16x16x32_bf16(af[i], bfr[j], acc[i][j], 0, 0, 0);
    __syncthreads();                      // WAR before next stage overwrites LDS
  }

  const int r0 = (lane >> 4) * 4, cl = lane & 15;
#pragma unroll
  for (int i = 0; i < 4; i++)
#pragma unroll
    for (int j = 0; j < 4; j++){
      int row = bm * 128 + wm + i * 16 + r0;
      int col = bn * 128 + wn + j * 16 + cl;
      u16* cp = C + (size_t)row * N + col;
#pragma unroll
      for (int r = 0; r < 4; r++) cp[(size_t)r * N] = f2bf(acc[i][j][r]);
    }
}

// ---------------- attention alpha: aS/aD[n][h] = sum_c HG[n][h*256+c]*a[h][c] ----------------
__global__ void alpha_k(const u16* __restrict__ HG, int ldH,
                        const float* __restrict__ a_s, const float* __restrict__ a_d,
                        float* __restrict__ aS, float* __restrict__ aD, int H)
{
  int n = blockIdx.x, h = blockIdx.y, lane = threadIdx.x;
  const u16* rp = HG + (size_t)n * ldH + h * 256 + lane * 4;
  ushort4 u = *(const ushort4*)rp;
  float4 av = *(const float4*)(a_s + h * 256 + lane * 4);
  float4 dv = *(const float4*)(a_d + h * 256 + lane * 4);
  float x0 = bf2f(u.x), x1 = bf2f(u.y), x2 = bf2f(u.z), x3 = bf2f(u.w);
  float s = x0 * av.x + x1 * av.y + x2 * av.z + x3 * av.w;
  float d = x0 * dv.x + x1 * dv.y + x2 * dv.z + x3 * dv.w;
#pragma unroll
  for (int off = 32; off; off >>= 1){ s += __shfl_down(s, off); d += __shfl_down(d, off); }
  if (lane == 0){ aS[(size_t)n * H + h] = s; aD[(size_t)n * H + h] = d; }
}

// ---------------- per-dst softmax + aggregate (one block per dst) ----------------
template<int H, bool FINAL>
__global__ __launch_bounds__(256)
void agg_k(const u16* __restrict__ HG, int ldH,
           const int* __restrict__ rowp, const int* __restrict__ esrc,
           const float* __restrict__ aS, const float* __restrict__ aD,
           const float* __restrict__ bias, const float* __restrict__ lbias,
           int gatCols, u16* __restrict__ outb, int ldo, float* __restrict__ outf)
{
  constexpr int PERT = H;          // channels per thread: H*256/256
  constexpr int MAXE = 256;
  __shared__ float s_m[H], s_dinv[H], s_red[4 * H];
  __shared__ float s_ew[MAXE * H];
  __shared__ float s_fin[FINAL ? 1536 : 4];

  const int dst = blockIdx.x;
  const int tid = threadIdx.x, lane = tid & 63, wv = tid >> 6;
  const int e0 = rowp[dst];
  const int deg = rowp[dst + 1] - e0;
  const int nE = deg + 1;          // + implicit self loop (index == deg)

  float adv[H];
#pragma unroll
  for (int h = 0; h < H; h++) adv[h] = aD[(size_t)dst * H + h];

  // ---- P1: segment max (stable softmax) ----
  float lm[H];
#pragma unroll
  for (int h = 0; h < H; h++) lm[h] = -1e30f;
  for (int i = tid; i < nE; i += 256){
    int s = (i == deg) ? dst : esrc[e0 + i];
#pragma unroll
    for (int h = 0; h < H; h++){
      float e = aS[(size_t)s * H + h] + adv[h];
      e = e > 0.f ? e : 0.2f * e;
      lm[h] = fmaxf(lm[h], e);
    }
  }
#pragma unroll
  for (int h = 0; h < H; h++)
#pragma unroll
    for (int off = 32; off; off >>= 1) lm[h] = fmaxf(lm[h], __shfl_down(lm[h], off));
  if (lane == 0){
#pragma unroll
    for (int h = 0; h < H; h++) s_red[wv * H + h] = lm[h];
  }
  __syncthreads();
  if (tid < H) s_m[tid] = fmaxf(fmaxf(s_red[tid], s_red[H + tid]),
                                fmaxf(s_red[2 * H + tid], s_red[3 * H + tid]));
  __syncthreads();

  // ---- P2: sum of exp (cache per-edge weights in LDS) ----
  float ls[H];
#pragma unroll
  for (int h = 0; h < H; h++) ls[h] = 0.f;
  for (int i = tid; i < nE; i += 256){
    int s = (i == deg) ? dst : esrc[e0 + i];
#pragma unroll
    for (int h = 0; h < H; h++){
      float e = aS[(size_t)s * H + h] + adv[h];
      e = e > 0.f ? e : 0.2f * e;
      float w = __expf(e - s_m[h]);
      if (i < MAXE) s_ew[i * H + h] = w;
      ls[h] += w;
    }
  }
#pragma unroll
  for (int h = 0; h < H; h++)
#pragma unroll
    for (int off = 32; off; off >>= 1) ls[h] += __shfl_down(ls[h], off);
  if (lane == 0){
#pragma unroll
    for (int h = 0; h < H; h++) s_red[wv * H + h] = ls[h];
  }
  __syncthreads();
  if (tid < H) s_dinv[tid] = 1.f / (s_red[tid] + s_red[H + tid] + s_red[2 * H + tid] + s_red[3 * H + tid] + 1e-16f);
  __syncthreads();

  // ---- P3: weighted gather-accumulate over edges ----
  float acc[PERT];
#pragma unroll
  for (int c = 0; c < PERT; c++) acc[c] = 0.f;
  const int ch0 = tid * PERT;

  if constexpr (H == 4){
    const int hh = tid >> 6;              // 64 threads per head
    const float dinv = s_dinv[hh];
    for (int i = 0; i < nE; i++){
      int s = (i == deg) ? dst : esrc[e0 + i];
      float w;
      if (i < MAXE) w = s_ew[i * 4 + hh];
      else {
        float e = aS[(size_t)s * 4 + hh] + aD[(size_t)dst * 4 + hh];
        e = e > 0.f ? e : 0.2f * e;
        w = __expf(e - s_m[hh]);
      }
      float cfc = w * dinv;
      const u16* rp = HG + (size_t)s * ldH;
      ushort4 u = *(const ushort4*)(rp + ch0);
      acc[0] += cfc * bf2f(u.x); acc[1] += cfc * bf2f(u.y);
      acc[2] += cfc * bf2f(u.z); acc[3] += cfc * bf2f(u.w);
    }
  } else {
    const int h0 = ch0 >> 8;
    const int h1 = (ch0 + 5) >> 8;        // h0 or h0+1
    const float dinv0 = s_dinv[h0], dinv1 = s_dinv[h1];
    const int bnd = (h0 + 1) * 256;
    for (int i = 0; i < nE; i++){
      int s = (i == deg) ? dst : esrc[e0 + i];
      float w0, w1;
      if (i < MAXE){ w0 = s_ew[i * 6 + h0]; w1 = s_ew[i * 6 + h1]; }
      else {
        float ea = aS[(size_t)s * 6 + h0] + aD[(size_t)dst * 6 + h0];
        ea = ea > 0.f ? ea : 0.2f * ea;
        w0 = __expf(ea - s_m[h0]);
        float eb = aS[(size_t)s * 6 + h1] + aD[(size_t)dst * 6 + h1];
        eb = eb > 0.f ? eb : 0.2f * eb;
        w1 = __expf(eb - s_m[h1]);
      }
      float c0 = w0 * dinv0, c1 = w1 * dinv1;
      const u32* rp4 = (const u32*)(HG + (size_t)s * ldH);
      u32 u0 = rp4[tid * 3], u1 = rp4[tid * 3 + 1], u2 = rp4[tid * 3 + 2];
      float v[6] = { bf2f((u16)(u0 & 0xffff)), bf2f((u16)(u0 >> 16)),
                     bf2f((u16)(u1 & 0xffff)), bf2f((u16)(u1 >> 16)),
                     bf2f((u16)(u2 & 0xffff)), bf2f((u16)(u2 >> 16)) };
#pragma unroll
      for (int c = 0; c < 6; c++) acc[c] += ((ch0 + c) < bnd ? c0 : c1) * v[c];
    }
  }

  // ---- epilogue ----
  if constexpr (FINAL){
#pragma unroll
    for (int c = 0; c < PERT; c++) s_fin[ch0 + c] = acc[c];
    __syncthreads();
    int c = tid;
    float v = 0.f;
#pragma unroll
    for (int h = 0; h < 6; h++) v += s_fin[h * 256 + c];
    v = v * (1.f / 6.f) + bias[c] + bf2f(HG[(size_t)dst * ldH + gatCols + c]) + lbias[c];
    outf[(size_t)dst * 256 + c] = v;
  } else {
    const u16* lr = HG + (size_t)dst * ldH + gatCols;
    ushort4 u = *(const ushort4*)(lr + ch0);
    float lv[4] = { bf2f(u.x), bf2f(u.y), bf2f(u.z), bf2f(u.w) };
    ushort4 o;
    float v0 = acc[0] + bias[ch0 + 0] + lv[0] + lbias[ch0 + 0]; v0 = v0 > 0.f ? v0 : __expf(v0) - 1.f;
    float v1 = acc[1] + bias[ch0 + 1] + lv[1] + lbias[ch0 + 1]; v1 = v1 > 0.f ? v1 : __expf(v1) - 1.f;
    float v2 = acc[2] + bias[ch0 + 2] + lv[2] + lbias[ch0 + 2]; v2 = v2 > 0.f ? v2 : __expf(v2) - 1.f;
    float v3 = acc[3] + bias[ch0 + 3] + lv[3] + lbias[ch0 + 3]; v3 = v3 > 0.f ? v3 : __expf(v3) - 1.f;
    o.x = f2bf(v0); o.y = f2bf(v1); o.z = f2bf(v2); o.w = f2bf(v3);
    *(ushort4*)(outb + (size_t)dst * ldo + ch0) = o;
  }
}

// ---------------- host orchestration ----------------
extern "C" void kernel_launch(void* const* d_in, const int* in_sizes, int n_in,
                              void* d_out, int out_size, void* d_ws, size_t ws_size,
                              hipStream_t stream)
{
  const float* x   = (const float*)d_in[0];
  const int*   ei  = (const int*)  d_in[1];
  const float* W1  = (const float*)d_in[3];
  const float* as1 = (const float*)d_in[4];
  const float* ad1 = (const float*)d_in[5];
  const float* b1  = (const float*)d_in[6];
  const float* lw1 = (const float*)d_in[7];
  const float* lb1 = (const float*)d_in[8];
  const float* W2  = (const float*)d_in[9];
  const float* as2 = (const float*)d_in[10];
  const float* ad2 = (const float*)d_in[11];
  const float* b2  = (const float*)d_in[12];
  const float* lw2 = (const float*)d_in[13];
  const float* lb2 = (const float*)d_in[14];
  const float* W3  = (const float*)d_in[15];
  const float* as3 = (const float*)d_in[16];
  const float* ad3 = (const float*)d_in[17];
  const float* b3  = (const float*)d_in[18];
  const float* lw3 = (const float*)d_in[19];
  const float* lb3 = (const float*)d_in[20];

  char* wp = (char*)d_ws;
  auto nxt = [&](size_t b) -> void* {
    void* p = (void*)wp; wp += (b + 255) & ~(size_t)255; return p;
  };
  u16*  Wt1  = (u16*) nxt((size_t)2048 * 512  * 2);
  u16*  Wt2  = (u16*) nxt((size_t)2048 * 1024 * 2);
  u16*  Wt3  = (u16*) nxt((size_t)1792 * 1024 * 2);
  u16*  Xb   = (u16*) nxt((size_t)M_PAD * 1024 * 2);
  u16*  HG   = (u16*) nxt((size_t)M_PAD * 2048 * 2);
  float* aS  = (float*)nxt((size_t)N_NODES * 6 * 4);
  float* aD  = (float*)nxt((size_t)N_NODES * 6 * 4);
  int*  cnt  = (int*)  nxt((size_t)N_NODES * 4);
  int*  rowp = (int*)  nxt((size_t)(N_NODES + 1) * 4);
  int*  fill = (int*)  nxt((size_t)N_NODES * 4);
  int*  esrc = (int*)  nxt((size_t)E_EDGES * 4);

  // CSR by dst
  hipMemsetAsync(cnt, 0, (size_t)N_NODES * 4, stream);
  hist_k   <<<(E_EDGES + 255) / 256, 256, 0, stream>>>(ei, cnt);
  scan_k   <<<1, 1024, 0, stream>>>(cnt, rowp, N_NODES);
  copy_int_k<<<(N_NODES + 255) / 256, 256, 0, stream>>>(rowp, fill, N_NODES);
  scatter_k<<<(E_EDGES + 255) / 256, 256, 0, stream>>>(ei, fill, esrc);

  // weight transpose+cast into combined [Wgat | Wlin] K-major bf16
  dim3 tb(32, 8);
  tcast_k<<<dim3(1024 / 32, 512  / 32), tb, 0, stream>>>(W1,  1024, Wt1, 0,    512);
  tcast_k<<<dim3(1024 / 32, 512  / 32), tb, 0, stream>>>(lw1, 1024, Wt1, 1024, 512);
  tcast_k<<<dim3(1024 / 32, 1024 / 32), tb, 0, stream>>>(W2,  1024, Wt2, 0,    1024);
  tcast_k<<<dim3(1024 / 32, 1024 / 32), tb, 0, stream>>>(lw2, 1024, Wt2, 1024, 1024);
  tcast_k<<<dim3(1536 / 32, 1024 / 32), tb, 0, stream>>>(W3,  1536, Wt3, 0,    1024);
  tcast_k<<<dim3(256  / 32, 1024 / 32), tb, 0, stream>>>(lw3, 256,  Wt3, 1536, 1024);

  // x -> bf16 padded; zero pad rows of the 1024-wide layouts (layers 2/3 inputs)
  castx_k<<<dim3(512 / 256, M_PAD), 256, 0, stream>>>(x, Xb, N_NODES, 512);
  zpad_k <<<(96 * 1024 + 255) / 256, 256, 0, stream>>>(Xb + (size_t)N_NODES * 1024, 96 * 1024);

  const int MT = M_PAD / 128;   // 157

  // ---- layer 1 ----
  gemm_bf16<<<dim3(MT, 2048 / 128), 256, 0, stream>>>(Xb, Wt1, HG, 2048, 512);
  alpha_k  <<<dim3(N_NODES, 4), 64, 0, stream>>>(HG, 2048, as1, ad1, aS, aD, 4);
  agg_k<4, false><<<N_NODES, 256, 0, stream>>>(HG, 2048, rowp, esrc, aS, aD, b1, lb1, 1024, Xb, 1024, nullptr);

  // ---- layer 2 ----
  gemm_bf16<<<dim3(MT, 2048 / 128), 256, 0, stream>>>(Xb, Wt2, HG, 2048, 1024);
  alpha_k  <<<dim3(N_NODES, 4), 64, 0, stream>>>(HG, 2048, as2, ad2, aS, aD, 4);
  agg_k<4, false><<<N_NODES, 256, 0, stream>>>(HG, 2048, rowp, esrc, aS, aD, b2, lb2, 1024, Xb, 1024, nullptr);

  // ---- layer 3 ----
  gemm_bf16<<<dim3(MT, 1792 / 128), 256, 0, stream>>>(Xb, Wt3, HG, 1792, 1024);
  alpha_k  <<<dim3(N_NODES, 6), 64, 0, stream>>>(HG, 1792, as3, ad3, aS, aD, 6);
  int outRows = out_size / 256;   // 16384 — only these rows are needed
  agg_k<6, true><<<outRows, 256, 0, stream>>>(HG, 1792, rowp, esrc, aS, aD, b3, lb3, 1536, nullptr, 0, (float*)d_out);

  (void)in_sizes; (void)n_in; (void)ws_size;
}

// Round 2
// 909.122 us; speedup vs baseline: 1.0584x; 1.0584x over previous
//
#include <hip/hip_runtime.h>

// ---------------- constants (problem-fixed sizes) ----------------
#define N_NODES 20000
#define M_PAD   20096   // 157 * 128
#define E_EDGES 320000

typedef unsigned short u16;
typedef unsigned int   u32;
typedef __attribute__((ext_vector_type(8))) short bf16x8;
typedef __attribute__((ext_vector_type(4))) float f32x4;

__device__ __forceinline__ float bf2f(u16 u){
  u32 x = ((u32)u) << 16; float f; __builtin_memcpy(&f, &x, 4); return f;
}
__device__ __forceinline__ u16 f2bf(float f){
  u32 u; __builtin_memcpy(&u, &f, 4);
  u += 0x7fffu + ((u >> 16) & 1u);          // RNE
  return (u16)(u >> 16);
}

__device__ __forceinline__ void gl_lds16(const void* g, void* l){
  __builtin_amdgcn_global_load_lds((const __attribute__((address_space(1))) void*)g,
                                   (__attribute__((address_space(3))) void*)l, 16, 0, 0);
}

// ---------------- CSR build ----------------
__global__ void hist_k(const int* __restrict__ ei, int* __restrict__ cnt){
  int i = blockIdx.x * 256 + threadIdx.x;
  if (i < E_EDGES) atomicAdd(&cnt[ei[E_EDGES + i]], 1);
}

// single-block wave-shuffle scan: 2 barriers per 1024-chunk
__global__ void scan_k(const int* __restrict__ cnt, int* __restrict__ rowp, int n){
  __shared__ int wsum[16], wpre[16];
  __shared__ int carry;
  int tid = threadIdx.x, lane = tid & 63, wv = tid >> 6;
  if (tid == 0) carry = 0;
  __syncthreads();
  for (int base = 0; base < n; base += 1024){
    int i = base + tid;
    int v = (i < n) ? cnt[i] : 0;
    int incl = v;
#pragma unroll
    for (int d = 1; d < 64; d <<= 1){
      int t = __shfl_up(incl, d, 64);
      if (lane >= d) incl += t;
    }
    if (lane == 63) wsum[wv] = incl;
    __syncthreads();
    if (tid == 0){
      int s = carry;
#pragma unroll
      for (int w = 0; w < 16; w++){ wpre[w] = s; s += wsum[w]; }
      carry = s;
    }
    __syncthreads();
    if (i < n) rowp[i] = wpre[wv] + incl - v;   // exclusive prefix
  }
  __syncthreads();
  if (tid == 0) rowp[n] = carry;
}

__global__ void copy_int_k(const int* __restrict__ a, int* __restrict__ b, int n){
  int i = blockIdx.x * 256 + threadIdx.x; if (i < n) b[i] = a[i];
}

__global__ void scatter_k(const int* __restrict__ ei, int* __restrict__ fill, int* __restrict__ esrc){
  int i = blockIdx.x * 256 + threadIdx.x;
  if (i < E_EDGES){
    int d = ei[E_EDGES + i];
    int p = atomicAdd(&fill[d], 1);
    esrc[p] = ei[i];
  }
}

// ---------------- casts / transposes ----------------
// src fp32 [K][Nc] -> dst bf16 rows [n0+n][k], row stride ldd (=K)
__global__ void tcast_k(const float* __restrict__ src, int Nc, u16* __restrict__ dst, int n0, int ldd){
  __shared__ float tile[32][33];
  int kb = blockIdx.y * 32, nb = blockIdx.x * 32;
  int tx = threadIdx.x, ty = threadIdx.y;
#pragma unroll
  for (int r = 0; r < 32; r += 8)
    tile[ty + r][tx] = src[(size_t)(kb + ty + r) * Nc + nb + tx];
  __syncthreads();
#pragma unroll
  for (int r = 0; r < 32; r += 8){
    int n = nb + ty + r;
    dst[(size_t)(n0 + n) * ldd + kb + tx] = f2bf(tile[tx][ty + r]);
  }
}

// one row per block, 512 cols, float2 -> packed 2xbf16
__global__ void castx_k(const float* __restrict__ x, u16* __restrict__ o, int realRows){
  int r = blockIdx.x, c = threadIdx.x * 2;
  float2 v = (r < realRows) ? *(const float2*)(x + (size_t)r * 512 + c) : make_float2(0.f, 0.f);
  u32 pk = ((u32)f2bf(v.y) << 16) | (u32)f2bf(v.x);
  *(u32*)(o + (size_t)r * 512 + c) = pk;
}

__global__ void zpad_k(u16* __restrict__ p, int n){
  int i = blockIdx.x * 256 + threadIdx.x; if (i < n) p[i] = 0;
}

// ---------------- bf16 NT GEMM: C[M][N] = A[M][K] * Bt[N][K]^T ----------------
// 128x256 tile, BK=32, 256 threads (4 waves, each 64x128 = 4x8 MFMA 16x16x32)
// grid: (N/256 fast, M/128) -> consecutive blocks share A-tile; with NB=8 each
// XCD keeps a fixed 256-col B stripe resident in its L2.
__global__ __launch_bounds__(256, 2)
void gemm_bf16(const u16* __restrict__ A, const u16* __restrict__ Bt, u16* __restrict__ C,
               int N, int K)
{
  __shared__ __attribute__((aligned(16))) u16 lA[128 * 32];   //  8 KB
  __shared__ __attribute__((aligned(16))) u16 lB[256 * 32];   // 16 KB
  const int tid  = threadIdx.x;
  const int wave = tid >> 6, lane = tid & 63;
  const int bn = blockIdx.x, bm = blockIdx.y;
  const int wm = (wave >> 1) * 64, wn = (wave & 1) * 128;

  // staging: per wave-instruction 16 rows x 32 k (lane -> row lane/4, k (lane%4)*8)
  const int srow  = wave * 16 + (lane >> 2);
  const int skcol = (lane & 3) * 8;
  const u16* Ag0 = A  + (size_t)(bm * 128 + srow) * K + skcol;
  const u16* Ag1 = Ag0 + (size_t)64 * K;
  const u16* Bg  = Bt + (size_t)(bn * 256 + srow) * K + skcol;
  u16* lA0 = lA + wave * 512; u16* lA1 = lA + 2048 + wave * 512;
  u16* lBw = lB + wave * 512;

  f32x4 acc[4][8] = {};

  for (int k0 = 0; k0 < K; k0 += 32){
    gl_lds16(Ag0 + k0, lA0);
    gl_lds16(Ag1 + k0, lA1);
#pragma unroll
    for (int c = 0; c < 4; c++)
      gl_lds16(Bg + (size_t)(c * 64) * K + k0, lBw + c * 2048);
    __syncthreads();                      // drain vmcnt -> LDS tiles ready
    const int koff = (lane >> 4) * 8;
    const int rsel = lane & 15;
    bf16x8 af[4], bfr[8];
#pragma unroll
    for (int i = 0; i < 4; i++) af[i]  = *(const bf16x8*)&lA[(wm + i * 16 + rsel) * 32 + koff];
#pragma unroll
    for (int j = 0; j < 8; j++) bfr[j] = *(const bf16x8*)&lB[(wn + j * 16 + rsel) * 32 + koff];
#pragma unroll
    for (int i = 0; i < 4; i++)
#pragma unroll
      for (int j = 0; j < 8; j++)
        acc[i][j] = __builtin_amdgcn_mfma_f32_16x16x32_bf16(af[i], bfr[j], acc[i][j], 0, 0, 0);
    __syncthreads();                      // WAR before next stage overwrites LDS
  }

  const int r0 = (lane >> 4) * 4, cl = lane & 15;
#pragma unroll
  for (int i = 0; i < 4; i++)
#pragma unroll
    for (int j = 0; j < 8; j++){
      int row = bm * 128 + wm + i * 16 + r0;
      int col = bn * 256 + wn + j * 16 + cl;
      u16* cp = C + (size_t)row * N + col;
#pragma unroll
      for (int r = 0; r < 4; r++) cp[(size_t)r * N] = f2bf(acc[i][j][r]);
    }
}

// ---------------- attention alpha: aS/aD[n][h] = sum_c HG[n][h*256+c]*a[h][c] ----------------
__global__ void alpha_k(const u16* __restrict__ HG, int ldH,
                        const float* __restrict__ a_s, const float* __restrict__ a_d,
                        float* __restrict__ aS, float* __restrict__ aD, int H)
{
  int n = blockIdx.x, h = blockIdx.y, lane = threadIdx.x;
  const u16* rp = HG + (size_t)n * ldH + h * 256 + lane * 4;
  ushort4 u = *(const ushort4*)rp;
  float4 av = *(const float4*)(a_s + h * 256 + lane * 4);
  float4 dv = *(const float4*)(a_d + h * 256 + lane * 4);
  float x0 = bf2f(u.x), x1 = bf2f(u.y), x2 = bf2f(u.z), x3 = bf2f(u.w);
  float s = x0 * av.x + x1 * av.y + x2 * av.z + x3 * av.w;
  float d = x0 * dv.x + x1 * dv.y + x2 * dv.z + x3 * dv.w;
#pragma unroll
  for (int off = 32; off; off >>= 1){ s += __shfl_down(s, off); d += __shfl_down(d, off); }
  if (lane == 0){ aS[(size_t)n * H + h] = s; aD[(size_t)n * H + h] = d; }
}

// ---------------- per-dst softmax + aggregate (one block per dst) ----------------
template<int H, bool FINAL>
__global__ __launch_bounds__(256)
void agg_k(const u16* __restrict__ HG, int ldH,
           const int* __restrict__ rowp, const int* __restrict__ esrc,
           const float* __restrict__ aS, const float* __restrict__ aD,
           const float* __restrict__ bias, const float* __restrict__ lbias,
           int gatCols, u16* __restrict__ outb, int ldo, float* __restrict__ outf)
{
  constexpr int PERT = H;          // channels per thread: H*256/256
  constexpr int MAXE = 320;
  __shared__ float s_m[H], s_dinv[H], s_red[4 * H];
  __shared__ float s_ew[MAXE * H];
  __shared__ int   s_src[MAXE];
  __shared__ float s_fin[FINAL ? 1536 : 4];

  const int dst = blockIdx.x;
  const int tid = threadIdx.x, lane = tid & 63, wv = tid >> 6;
  const int e0 = rowp[dst];
  const int deg = rowp[dst + 1] - e0;
  const int nE = deg + 1;          // + implicit self loop (index == deg)
  const bool fits = (nE <= MAXE);

  float adv[H];
#pragma unroll
  for (int h = 0; h < H; h++) adv[h] = aD[(size_t)dst * H + h];

  // ---- P1: segment max; cache src idx + logits in LDS ----
  float lm[H];
#pragma unroll
  for (int h = 0; h < H; h++) lm[h] = -1e30f;
  for (int i = tid; i < nE; i += 256){
    int s = (i == deg) ? dst : esrc[e0 + i];
    if (fits) s_src[i] = s;
#pragma unroll
    for (int h = 0; h < H; h++){
      float e = aS[(size_t)s * H + h] + adv[h];
      e = e > 0.f ? e : 0.2f * e;
      if (fits) s_ew[i * H + h] = e;
      lm[h] = fmaxf(lm[h], e);
    }
  }
#pragma unroll
  for (int h = 0; h < H; h++)
#pragma unroll
    for (int off = 32; off; off >>= 1) lm[h] = fmaxf(lm[h], __shfl_down(lm[h], off));
  if (lane == 0){
#pragma unroll
    for (int h = 0; h < H; h++) s_red[wv * H + h] = lm[h];
  }
  __syncthreads();
  if (tid < H) s_m[tid] = fmaxf(fmaxf(s_red[tid], s_red[H + tid]),
                                fmaxf(s_red[2 * H + tid], s_red[3 * H + tid]));
  __syncthreads();

  // ---- P2: sum of exp (logits already in LDS; same-thread indices) ----
  float ls[H];
#pragma unroll
  for (int h = 0; h < H; h++) ls[h] = 0.f;
  for (int i = tid; i < nE; i += 256){
    if (fits){
#pragma unroll
      for (int h = 0; h < H; h++){
        float w = __expf(s_ew[i * H + h] - s_m[h]);
        s_ew[i * H + h] = w;
        ls[h] += w;
      }
    } else {
      int s = (i == deg) ? dst : esrc[e0 + i];
#pragma unroll
      for (int h = 0; h < H; h++){
        float e = aS[(size_t)s * H + h] + adv[h];
        e = e > 0.f ? e : 0.2f * e;
        ls[h] += __expf(e - s_m[h]);
      }
    }
  }
#pragma unroll
  for (int h = 0; h < H; h++)
#pragma unroll
    for (int off = 32; off; off >>= 1) ls[h] += __shfl_down(ls[h], off);
  if (lane == 0){
#pragma unroll
    for (int h = 0; h < H; h++) s_red[wv * H + h] = ls[h];
  }
  __syncthreads();
  if (tid < H) s_dinv[tid] = 1.f / (s_red[tid] + s_red[H + tid] + s_red[2 * H + tid] + s_red[3 * H + tid] + 1e-16f);
  __syncthreads();

  // ---- P3: weighted gather-accumulate over edges (x2 unrolled) ----
  float acc[PERT];
#pragma unroll
  for (int c = 0; c < PERT; c++) acc[c] = 0.f;
  const int ch0 = tid * PERT;

  if constexpr (H == 4){
    const int hh = tid >> 6;              // 64 threads per head
    const float dinv = s_dinv[hh];
    const u16* HGb = HG + ch0;
    if (fits){
      int i = 0;
      for (; i + 2 <= nE; i += 2){
        int s0 = s_src[i], s1 = s_src[i + 1];
        float w0 = s_ew[i * 4 + hh] * dinv;
        float w1 = s_ew[i * 4 + 4 + hh] * dinv;
        ushort4 u0 = *(const ushort4*)(HGb + (size_t)s0 * ldH);
        ushort4 u1 = *(const ushort4*)(HGb + (size_t)s1 * ldH);
        acc[0] += w0 * bf2f(u0.x) + w1 * bf2f(u1.x);
        acc[1] += w0 * bf2f(u0.y) + w1 * bf2f(u1.y);
        acc[2] += w0 * bf2f(u0.z) + w1 * bf2f(u1.z);
        acc[3] += w0 * bf2f(u0.w) + w1 * bf2f(u1.w);
      }
      if (i < nE){
        int s0 = s_src[i];
        float w0 = s_ew[i * 4 + hh] * dinv;
        ushort4 u0 = *(const ushort4*)(HGb + (size_t)s0 * ldH);
        acc[0] += w0 * bf2f(u0.x); acc[1] += w0 * bf2f(u0.y);
        acc[2] += w0 * bf2f(u0.z); acc[3] += w0 * bf2f(u0.w);
      }
    } else {
      for (int i = 0; i < nE; i++){
        int s = (i == deg) ? dst : esrc[e0 + i];
        float e = aS[(size_t)s * 4 + hh] + adv[hh];
        e = e > 0.f ? e : 0.2f * e;
        float w = __expf(e - s_m[hh]) * dinv;
        ushort4 u = *(const ushort4*)(HGb + (size_t)s * ldH);
        acc[0] += w * bf2f(u.x); acc[1] += w * bf2f(u.y);
        acc[2] += w * bf2f(u.z); acc[3] += w * bf2f(u.w);
      }
    }
  } else {
    const int h0 = ch0 >> 8;
    const int h1 = (ch0 + 5) >> 8;        // h0 or h0+1
    const float dinv0 = s_dinv[h0], dinv1 = s_dinv[h1];
    const int bnd = (h0 + 1) * 256;
    const u32* HGb = (const u32*)HG;      // tid*3 dwords into each row
    const int rowd = ldH >> 1;
    if (fits){
      int i = 0;
      for (; i + 2 <= nE; i += 2){
        int s0 = s_src[i], s1 = s_src[i + 1];
        float p0 = s_ew[i * 6 + h0] * dinv0, q0 = s_ew[i * 6 + h1] * dinv1;
        float p1 = s_ew[i * 6 + 6 + h0] * dinv0, q1 = s_ew[i * 6 + 6 + h1] * dinv1;
        const u32* r0p = HGb + (size_t)s0 * rowd + tid * 3;
        const u32* r1p = HGb + (size_t)s1 * rowd + tid * 3;
        u32 a0 = r0p[0], a1 = r0p[1], a2 = r0p[2];
        u32 b0 = r1p[0], b1 = r1p[1], b2 = r1p[2];
        float v0[6] = { bf2f((u16)(a0 & 0xffff)), bf2f((u16)(a0 >> 16)),
                        bf2f((u16)(a1 & 0xffff)), bf2f((u16)(a1 >> 16)),
                        bf2f((u16)(a2 & 0xffff)), bf2f((u16)(a2 >> 16)) };
        float v1[6] = { bf2f((u16)(b0 & 0xffff)), bf2f((u16)(b0 >> 16)),
                        bf2f((u16)(b1 & 0xffff)), bf2f((u16)(b1 >> 16)),
                        bf2f((u16)(b2 & 0xffff)), bf2f((u16)(b2 >> 16)) };
#pragma unroll
        for (int c = 0; c < 6; c++){
          bool lo = (ch0 + c) < bnd;
          acc[c] += (lo ? p0 : q0) * v0[c] + (lo ? p1 : q1) * v1[c];
        }
      }
      if (i < nE){
        int s0 = s_src[i];
        float p0 = s_ew[i * 6 + h0] * dinv0, q0 = s_ew[i * 6 + h1] * dinv1;
        const u32* r0p = HGb + (size_t)s0 * rowd + tid * 3;
        u32 a0 = r0p[0], a1 = r0p[1], a2 = r0p[2];
        float v0[6] = { bf2f((u16)(a0 & 0xffff)), bf2f((u16)(a0 >> 16)),
                        bf2f((u16)(a1 & 0xffff)), bf2f((u16)(a1 >> 16)),
                        bf2f((u16)(a2 & 0xffff)), bf2f((u16)(a2 >> 16)) };
#pragma unroll
        for (int c = 0; c < 6; c++) acc[c] += (((ch0 + c) < bnd) ? p0 : q0) * v0[c];
      }
    } else {
      for (int i = 0; i < nE; i++){
        int s = (i == deg) ? dst : esrc[e0 + i];
        float ea = aS[(size_t)s * 6 + h0] + adv[h0];
        ea = ea > 0.f ? ea : 0.2f * ea;
        float p0 = __expf(ea - s_m[h0]) * dinv0;
        float eb = aS[(size_t)s * 6 + h1] + adv[h1];
        eb = eb > 0.f ? eb : 0.2f * eb;
        float q0 = __expf(eb - s_m[h1]) * dinv1;
        const u32* r0p = HGb + (size_t)s * rowd + tid * 3;
        u32 a0 = r0p[0], a1 = r0p[1], a2 = r0p[2];
        float v0[6] = { bf2f((u16)(a0 & 0xffff)), bf2f((u16)(a0 >> 16)),
                        bf2f((u16)(a1 & 0xffff)), bf2f((u16)(a1 >> 16)),
                        bf2f((u16)(a2 & 0xffff)), bf2f((u16)(a2 >> 16)) };
#pragma unroll
        for (int c = 0; c < 6; c++) acc[c] += (((ch0 + c) < bnd) ? p0 : q0) * v0[c];
      }
    }
  }

  // ---- epilogue ----
  if constexpr (FINAL){
#pragma unroll
    for (int c = 0; c < PERT; c++) s_fin[ch0 + c] = acc[c];
    __syncthreads();
    int c = tid;
    float v = 0.f;
#pragma unroll
    for (int h = 0; h < 6; h++) v += s_fin[h * 256 + c];
    v = v * (1.f / 6.f) + bias[c] + bf2f(HG[(size_t)dst * ldH + gatCols + c]) + lbias[c];
    outf[(size_t)dst * 256 + c] = v;
  } else {
    const u16* lr = HG + (size_t)dst * ldH + gatCols;
    ushort4 u = *(const ushort4*)(lr + ch0);
    float lv[4] = { bf2f(u.x), bf2f(u.y), bf2f(u.z), bf2f(u.w) };
    ushort4 o;
    float v0 = acc[0] + bias[ch0 + 0] + lv[0] + lbias[ch0 + 0]; v0 = v0 > 0.f ? v0 : __expf(v0) - 1.f;
    float v1 = acc[1] + bias[ch0 + 1] + lv[1] + lbias[ch0 + 1]; v1 = v1 > 0.f ? v1 : __expf(v1) - 1.f;
    float v2 = acc[2] + bias[ch0 + 2] + lv[2] + lbias[ch0 + 2]; v2 = v2 > 0.f ? v2 : __expf(v2) - 1.f;
    float v3 = acc[3] + bias[ch0 + 3] + lv[3] + lbias[ch0 + 3]; v3 = v3 > 0.f ? v3 : __expf(v3) - 1.f;
    o.x = f2bf(v0); o.y = f2bf(v1); o.z = f2bf(v2); o.w = f2bf(v3);
    *(ushort4*)(outb + (size_t)dst * ldo + ch0) = o;
  }
}

// ---------------- host orchestration ----------------
extern "C" void kernel_launch(void* const* d_in, const int* in_sizes, int n_in,
                              void* d_out, int out_size, void* d_ws, size_t ws_size,
                              hipStream_t stream)
{
  const float* x   = (const float*)d_in[0];
  const int*   ei  = (const int*)  d_in[1];
  const float* W1  = (const float*)d_in[3];
  const float* as1 = (const float*)d_in[4];
  const float* ad1 = (const float*)d_in[5];
  const float* b1  = (const float*)d_in[6];
  const float* lw1 = (const float*)d_in[7];
  const float* lb1 = (const float*)d_in[8];
  const float* W2  = (const float*)d_in[9];
  const float* as2 = (const float*)d_in[10];
  const float* ad2 = (const float*)d_in[11];
  const float* b2  = (const float*)d_in[12];
  const float* lw2 = (const float*)d_in[13];
  const float* lb2 = (const float*)d_in[14];
  const float* W3  = (const float*)d_in[15];
  const float* as3 = (const float*)d_in[16];
  const float* ad3 = (const float*)d_in[17];
  const float* b3  = (const float*)d_in[18];
  const float* lw3 = (const float*)d_in[19];
  const float* lb3 = (const float*)d_in[20];

  char* wp = (char*)d_ws;
  auto nxt = [&](size_t b) -> void* {
    void* p = (void*)wp; wp += (b + 255) & ~(size_t)255; return p;
  };
  u16*  Wt1  = (u16*) nxt((size_t)2048 * 512  * 2);
  u16*  Wt2  = (u16*) nxt((size_t)2048 * 1024 * 2);
  u16*  Wt3  = (u16*) nxt((size_t)1792 * 1024 * 2);
  u16*  Xb   = (u16*) nxt((size_t)M_PAD * 1024 * 2);
  u16*  HG   = (u16*) nxt((size_t)M_PAD * 2048 * 2);
  float* aS  = (float*)nxt((size_t)N_NODES * 6 * 4);
  float* aD  = (float*)nxt((size_t)N_NODES * 6 * 4);
  int*  cnt  = (int*)  nxt((size_t)N_NODES * 4);
  int*  rowp = (int*)  nxt((size_t)(N_NODES + 1) * 4);
  int*  fill = (int*)  nxt((size_t)N_NODES * 4);
  int*  esrc = (int*)  nxt((size_t)E_EDGES * 4);

  // CSR by dst
  hipMemsetAsync(cnt, 0, (size_t)N_NODES * 4, stream);
  hist_k   <<<(E_EDGES + 255) / 256, 256, 0, stream>>>(ei, cnt);
  scan_k   <<<1, 1024, 0, stream>>>(cnt, rowp, N_NODES);
  copy_int_k<<<(N_NODES + 255) / 256, 256, 0, stream>>>(rowp, fill, N_NODES);
  scatter_k<<<(E_EDGES + 255) / 256, 256, 0, stream>>>(ei, fill, esrc);

  // weight transpose+cast into combined [Wgat | Wlin] K-major bf16
  dim3 tb(32, 8);
  tcast_k<<<dim3(1024 / 32, 512  / 32), tb, 0, stream>>>(W1,  1024, Wt1, 0,    512);
  tcast_k<<<dim3(1024 / 32, 512  / 32), tb, 0, stream>>>(lw1, 1024, Wt1, 1024, 512);
  tcast_k<<<dim3(1024 / 32, 1024 / 32), tb, 0, stream>>>(W2,  1024, Wt2, 0,    1024);
  tcast_k<<<dim3(1024 / 32, 1024 / 32), tb, 0, stream>>>(lw2, 1024, Wt2, 1024, 1024);
  tcast_k<<<dim3(1536 / 32, 1024 / 32), tb, 0, stream>>>(W3,  1536, Wt3, 0,    1024);
  tcast_k<<<dim3(256  / 32, 1024 / 32), tb, 0, stream>>>(lw3, 256,  Wt3, 1536, 1024);

  // x -> bf16 padded; zero pad rows of the 1024-wide layouts (layers 2/3 inputs)
  castx_k<<<M_PAD, 256, 0, stream>>>(x, Xb, N_NODES);
  zpad_k <<<(96 * 1024 + 255) / 256, 256, 0, stream>>>(Xb + (size_t)N_NODES * 1024, 96 * 1024);

  const int MT = M_PAD / 128;   // 157

  // ---- layer 1 ----
  gemm_bf16<<<dim3(2048 / 256, MT), 256, 0, stream>>>(Xb, Wt1, HG, 2048, 512);
  alpha_k  <<<dim3(N_NODES, 4), 64, 0, stream>>>(HG, 2048, as1, ad1, aS, aD, 4);
  agg_k<4, false><<<N_NODES, 256, 0, stream>>>(HG, 2048, rowp, esrc, aS, aD, b1, lb1, 1024, Xb, 1024, nullptr);

  // ---- layer 2 ----
  gemm_bf16<<<dim3(2048 / 256, MT), 256, 0, stream>>>(Xb, Wt2, HG, 2048, 1024);
  alpha_k  <<<dim3(N_NODES, 4), 64, 0, stream>>>(HG, 2048, as2, ad2, aS, aD, 4);
  agg_k<4, false><<<N_NODES, 256, 0, stream>>>(HG, 2048, rowp, esrc, aS, aD, b2, lb2, 1024, Xb, 1024, nullptr);

  // ---- layer 3 ----
  gemm_bf16<<<dim3(1792 / 256, MT), 256, 0, stream>>>(Xb, Wt3, HG, 1792, 1024);
  alpha_k  <<<dim3(N_NODES, 6), 64, 0, stream>>>(HG, 1792, as3, ad3, aS, aD, 6);
  int outRows = out_size / 256;   // 16384 — only these rows are needed
  agg_k<6, true><<<outRows, 256, 0, stream>>>(HG, 1792, rowp, esrc, aS, aD, b3, lb3, 1536, nullptr, 0, (float*)d_out);

  (void)in_sizes; (void)n_in; (void)ws_size;
}

// Round 3
// 873.747 us; speedup vs baseline: 1.1012x; 1.0405x over previous
//
#include <hip/hip_runtime.h>

// ---------------- constants (problem-fixed sizes) ----------------
#define N_NODES 20000
#define M_PAD   20096   // 157 * 128
#define E_EDGES 320000

typedef unsigned short u16;
typedef unsigned int   u32;
typedef __attribute__((ext_vector_type(8))) short bf16x8;
typedef __attribute__((ext_vector_type(4))) float f32x4;
typedef __attribute__((ext_vector_type(4))) u32   u32x4;

__device__ __forceinline__ float bf2f(u16 u){
  u32 x = ((u32)u) << 16; float f; __builtin_memcpy(&f, &x, 4); return f;
}
__device__ __forceinline__ u16 f2bf(float f){
  u32 u; __builtin_memcpy(&u, &f, 4);
  u += 0x7fffu + ((u >> 16) & 1u);          // RNE
  return (u16)(u >> 16);
}

__device__ __forceinline__ void gl_lds16(const void* g, void* l){
  __builtin_amdgcn_global_load_lds((const __attribute__((address_space(1))) void*)g,
                                   (__attribute__((address_space(3))) void*)l, 16, 0, 0);
}

__device__ __forceinline__ void acc8(float* acc, float w, u32x4 p){
#pragma unroll
  for (int d = 0; d < 4; d++){
    u32 u = p[d];
    acc[2 * d]     += w * bf2f((u16)(u & 0xffff));
    acc[2 * d + 1] += w * bf2f((u16)(u >> 16));
  }
}

// ---------------- CSR build ----------------
__global__ void hist_k(const int* __restrict__ ei, int* __restrict__ cnt){
  int i = blockIdx.x * 256 + threadIdx.x;
  if (i < E_EDGES) atomicAdd(&cnt[ei[E_EDGES + i]], 1);
}

// single-block wave-shuffle scan; also writes the fill[] working copy
__global__ void scan_k(const int* __restrict__ cnt, int* __restrict__ rowp,
                       int* __restrict__ fill, int n){
  __shared__ int wsum[16], wpre[16];
  __shared__ int carry;
  int tid = threadIdx.x, lane = tid & 63, wv = tid >> 6;
  if (tid == 0) carry = 0;
  __syncthreads();
  for (int base = 0; base < n; base += 1024){
    int i = base + tid;
    int v = (i < n) ? cnt[i] : 0;
    int incl = v;
#pragma unroll
    for (int d = 1; d < 64; d <<= 1){
      int t = __shfl_up(incl, d, 64);
      if (lane >= d) incl += t;
    }
    if (lane == 63) wsum[wv] = incl;
    __syncthreads();
    if (tid == 0){
      int s = carry;
#pragma unroll
      for (int w = 0; w < 16; w++){ wpre[w] = s; s += wsum[w]; }
      carry = s;
    }
    __syncthreads();
    if (i < n){ int e = wpre[wv] + incl - v; rowp[i] = e; fill[i] = e; }
  }
  __syncthreads();
  if (tid == 0) rowp[n] = carry;
}

__global__ void scatter_k(const int* __restrict__ ei, int* __restrict__ fill, int* __restrict__ esrc){
  int i = blockIdx.x * 256 + threadIdx.x;
  if (i < E_EDGES){
    int d = ei[E_EDGES + i];
    int p = atomicAdd(&fill[d], 1);
    esrc[p] = ei[i];
  }
}

// ---------------- weight transpose+cast, all 6 jobs in one kernel ----------------
// src fp32 [K][Nc] -> dst bf16 rows [n0+n][k]
__global__ void tcast_all(const float* __restrict__ W1, const float* __restrict__ lw1, u16* __restrict__ Wt1,
                          const float* __restrict__ W2, const float* __restrict__ lw2, u16* __restrict__ Wt2,
                          const float* __restrict__ W3, const float* __restrict__ lw3, u16* __restrict__ Wt3)
{
  __shared__ float tile[32][33];
  int b = blockIdx.x;
  const float* src; u16* dst; int Nc, n0, ldd;
  if      (b <  512){            src = W1;  Nc = 1024; dst = Wt1; n0 = 0;    ldd = 512;  }
  else if (b < 1024){ b -=  512; src = lw1; Nc = 1024; dst = Wt1; n0 = 1024; ldd = 512;  }
  else if (b < 2048){ b -= 1024; src = W2;  Nc = 1024; dst = Wt2; n0 = 0;    ldd = 1024; }
  else if (b < 3072){ b -= 2048; src = lw2; Nc = 1024; dst = Wt2; n0 = 1024; ldd = 1024; }
  else if (b < 4608){ b -= 3072; src = W3;  Nc = 1536; dst = Wt3; n0 = 0;    ldd = 1024; }
  else              { b -= 4608; src = lw3; Nc = 256;  dst = Wt3; n0 = 1536; ldd = 1024; }
  int gx = Nc / 32;
  int kb = (b / gx) * 32, nb = (b % gx) * 32;
  int tx = threadIdx.x, ty = threadIdx.y;
#pragma unroll
  for (int r = 0; r < 32; r += 8)
    tile[ty + r][tx] = src[(size_t)(kb + ty + r) * Nc + nb + tx];
  __syncthreads();
#pragma unroll
  for (int r = 0; r < 32; r += 8){
    int n = nb + ty + r;
    dst[(size_t)(n0 + n) * ldd + kb + tx] = f2bf(tile[tx][ty + r]);
  }
}

// one row per block, 512 cols, float2 -> packed 2xbf16
__global__ void castx_k(const float* __restrict__ x, u16* __restrict__ o, int realRows){
  int r = blockIdx.x, c = threadIdx.x * 2;
  float2 v = (r < realRows) ? *(const float2*)(x + (size_t)r * 512 + c) : make_float2(0.f, 0.f);
  u32 pk = ((u32)f2bf(v.y) << 16) | (u32)f2bf(v.x);
  *(u32*)(o + (size_t)r * 512 + c) = pk;
}

__global__ void zpad_k(u16* __restrict__ p, int n){
  int i = blockIdx.x * 256 + threadIdx.x; if (i < n) p[i] = 0;
}

// ---------------- bf16 NT GEMM + fused alpha epilogue ----------------
// C[M][N] = A[M][K] * Bt[N][K]^T ; 128x256 tile, BK=32, 256 threads.
// grid: (N/256 fast, M/128). bn tile == one attention head (256 cols); for
// bn < H the block also computes aS/aD = h . a_src/a_dst from f32 acc.
__global__ __launch_bounds__(256, 2)
void gemm_bf16(const u16* __restrict__ A, const u16* __restrict__ Bt, u16* __restrict__ C,
               int N, int K,
               const float* __restrict__ a_s, const float* __restrict__ a_d,
               float* __restrict__ aS, float* __restrict__ aD, int H)
{
  __shared__ __attribute__((aligned(16))) u16 lA[128 * 32];   //  8 KB
  __shared__ __attribute__((aligned(16))) u16 lB[256 * 32];   // 16 KB
  const int tid  = threadIdx.x;
  const int wave = tid >> 6, lane = tid & 63;
  const int bn = blockIdx.x, bm = blockIdx.y;
  const int wm = (wave >> 1) * 64, wn = (wave & 1) * 128;

  const int srow  = wave * 16 + (lane >> 2);
  const int skcol = (lane & 3) * 8;
  const u16* Ag0 = A  + (size_t)(bm * 128 + srow) * K + skcol;
  const u16* Ag1 = Ag0 + (size_t)64 * K;
  const u16* Bg  = Bt + (size_t)(bn * 256 + srow) * K + skcol;
  u16* lA0 = lA + wave * 512; u16* lA1 = lA + 2048 + wave * 512;
  u16* lBw = lB + wave * 512;

  f32x4 acc[4][8] = {};

  for (int k0 = 0; k0 < K; k0 += 32){
    gl_lds16(Ag0 + k0, lA0);
    gl_lds16(Ag1 + k0, lA1);
#pragma unroll
    for (int c = 0; c < 4; c++)
      gl_lds16(Bg + (size_t)(c * 64) * K + k0, lBw + c * 2048);
    __syncthreads();
    const int koff = (lane >> 4) * 8;
    const int rsel = lane & 15;
    bf16x8 af[4], bfr[8];
#pragma unroll
    for (int i = 0; i < 4; i++) af[i]  = *(const bf16x8*)&lA[(wm + i * 16 + rsel) * 32 + koff];
#pragma unroll
    for (int j = 0; j < 8; j++) bfr[j] = *(const bf16x8*)&lB[(wn + j * 16 + rsel) * 32 + koff];
#pragma unroll
    for (int i = 0; i < 4; i++)
#pragma unroll
      for (int j = 0; j < 8; j++)
        acc[i][j] = __builtin_amdgcn_mfma_f32_16x16x32_bf16(af[i], bfr[j], acc[i][j], 0, 0, 0);
    __syncthreads();
  }

  const int r0 = (lane >> 4) * 4, cl = lane & 15;
#pragma unroll
  for (int i = 0; i < 4; i++)
#pragma unroll
    for (int j = 0; j < 8; j++){
      int row = bm * 128 + wm + i * 16 + r0;
      int col = bn * 256 + wn + j * 16 + cl;
      u16* cp = C + (size_t)row * N + col;
#pragma unroll
      for (int r = 0; r < 4; r++) cp[(size_t)r * N] = f2bf(acc[i][j][r]);
    }

  // ---- fused alpha: aS/aD[row][bn] for gat heads ----
  if (bn < H){
    float* fa = (float*)lA;                 // [0..255]=a_s, [256..511]=a_d
    fa[tid]       = a_s[bn * 256 + tid];
    fa[256 + tid] = a_d[bn * 256 + tid];
    __syncthreads();
    float* fb = (float*)lB;                 // parts: s [0..255], d [256..511]
    const int q = lane >> 4;
#pragma unroll
    for (int i = 0; i < 4; i++)
#pragma unroll
      for (int r = 0; r < 4; r++){
        float ps = 0.f, pd = 0.f;
#pragma unroll
        for (int j = 0; j < 8; j++){
          float v = acc[i][j][r];
          int c = wn + j * 16 + cl;
          ps += v * fa[c];
          pd += v * fa[256 + c];
        }
#pragma unroll
        for (int m = 1; m < 16; m <<= 1){
          ps += __shfl_xor(ps, m, 64);
          pd += __shfl_xor(pd, m, 64);
        }
        if (cl == 0){
          int row = wm + i * 16 + q * 4 + r;
          fb[(wave & 1) * 128 + row]       = ps;
          fb[256 + (wave & 1) * 128 + row] = pd;
        }
      }
    __syncthreads();
    if (tid < 128){
      int row = bm * 128 + tid;
      aS[(size_t)row * H + bn] = fb[tid] + fb[128 + tid];
      aD[(size_t)row * H + bn] = fb[256 + tid] + fb[384 + tid];
    }
  }
}

// ---------------- H=4 softmax+aggregate: one block per dst, 2 edge-groups x 16B lanes ----------------
__global__ __launch_bounds__(256)
void agg4_k(const u16* __restrict__ HG, int ldH,
            const int* __restrict__ rowp, const int* __restrict__ esrc,
            const float* __restrict__ aS, const float* __restrict__ aD,
            const float* __restrict__ bias, const float* __restrict__ lbias,
            u16* __restrict__ outb)
{
  constexpr int MAXE = 320;
  __shared__ float s_m[4], s_dinv[4], s_red[16];
  __shared__ float s_ew[MAXE * 4];
  __shared__ int   s_src[MAXE];
  __shared__ float s_acc[2][1024];

  const int dst = blockIdx.x;
  const int tid = threadIdx.x, lane = tid & 63, wv = tid >> 6;
  const int e0 = rowp[dst];
  const int deg = rowp[dst + 1] - e0;
  const int nE = deg + 1;                   // + implicit self loop (index == deg)
  const bool fits = (nE <= MAXE);

  float4 adv = *(const float4*)(aD + (size_t)dst * 4);

  // ---- P1: segment max; cache src idx + leaky logits in LDS ----
  float lm[4] = { -1e30f, -1e30f, -1e30f, -1e30f };
  for (int i = tid; i < nE; i += 256){
    int s = (i == deg) ? dst : esrc[e0 + i];
    if (fits) s_src[i] = s;
    float4 as = *(const float4*)(aS + (size_t)s * 4);
    float e0h = as.x + adv.x; e0h = e0h > 0.f ? e0h : 0.2f * e0h;
    float e1h = as.y + adv.y; e1h = e1h > 0.f ? e1h : 0.2f * e1h;
    float e2h = as.z + adv.z; e2h = e2h > 0.f ? e2h : 0.2f * e2h;
    float e3h = as.w + adv.w; e3h = e3h > 0.f ? e3h : 0.2f * e3h;
    if (fits){ s_ew[i*4+0]=e0h; s_ew[i*4+1]=e1h; s_ew[i*4+2]=e2h; s_ew[i*4+3]=e3h; }
    lm[0] = fmaxf(lm[0], e0h); lm[1] = fmaxf(lm[1], e1h);
    lm[2] = fmaxf(lm[2], e2h); lm[3] = fmaxf(lm[3], e3h);
  }
#pragma unroll
  for (int h = 0; h < 4; h++)
#pragma unroll
    for (int off = 32; off; off >>= 1) lm[h] = fmaxf(lm[h], __shfl_down(lm[h], off));
  if (lane == 0){
#pragma unroll
    for (int h = 0; h < 4; h++) s_red[wv * 4 + h] = lm[h];
  }
  __syncthreads();
  if (tid < 4) s_m[tid] = fmaxf(fmaxf(s_red[tid], s_red[4 + tid]),
                                fmaxf(s_red[8 + tid], s_red[12 + tid]));
  __syncthreads();

  // ---- P2: sum of exp ----
  float ls[4] = {0.f, 0.f, 0.f, 0.f};
  for (int i = tid; i < nE; i += 256){
    if (fits){
#pragma unroll
      for (int h = 0; h < 4; h++){
        float w = __expf(s_ew[i * 4 + h] - s_m[h]);
        s_ew[i * 4 + h] = w;
        ls[h] += w;
      }
    } else {
      int s = (i == deg) ? dst : esrc[e0 + i];
      float4 as = *(const float4*)(aS + (size_t)s * 4);
      float e;
      e = as.x + adv.x; e = e > 0.f ? e : 0.2f * e; ls[0] += __expf(e - s_m[0]);
      e = as.y + adv.y; e = e > 0.f ? e : 0.2f * e; ls[1] += __expf(e - s_m[1]);
      e = as.z + adv.z; e = e > 0.f ? e : 0.2f * e; ls[2] += __expf(e - s_m[2]);
      e = as.w + adv.w; e = e > 0.f ? e : 0.2f * e; ls[3] += __expf(e - s_m[3]);
    }
  }
#pragma unroll
  for (int h = 0; h < 4; h++)
#pragma unroll
    for (int off = 32; off; off >>= 1) ls[h] += __shfl_down(ls[h], off);
  if (lane == 0){
#pragma unroll
    for (int h = 0; h < 4; h++) s_red[wv * 4 + h] = ls[h];
  }
  __syncthreads();
  if (tid < 4) s_dinv[tid] = 1.f / (s_red[tid] + s_red[4 + tid] + s_red[8 + tid] + s_red[12 + tid] + 1e-16f);
  __syncthreads();

  // ---- P3: 2 edge-groups (wave pair) x full row, 16B/lane ----
  const int grp = wv >> 1;                  // edge parity
  const int ch0 = (wv & 1) * 512 + lane * 8;
  const int h   = ch0 >> 8;
  const float dinv = s_dinv[h];
  const float mh   = s_m[h];
  float acc[8] = {};
  const u16* HGb = HG + ch0;

  if (fits){
    int i = grp;
    for (; i + 2 < nE; i += 4){
      int s0 = s_src[i], s1 = s_src[i + 2];
      float w0 = s_ew[i * 4 + h] * dinv;
      float w1 = s_ew[(i + 2) * 4 + h] * dinv;
      u32x4 p0 = *(const u32x4*)(HGb + (size_t)s0 * ldH);
      u32x4 p1 = *(const u32x4*)(HGb + (size_t)s1 * ldH);
      acc8(acc, w0, p0);
      acc8(acc, w1, p1);
    }
    if (i < nE){
      int s0 = s_src[i];
      float w0 = s_ew[i * 4 + h] * dinv;
      u32x4 p0 = *(const u32x4*)(HGb + (size_t)s0 * ldH);
      acc8(acc, w0, p0);
    }
  } else {
    float advh = aD[(size_t)dst * 4 + h];
    for (int i = grp; i < nE; i += 2){
      int s = (i == deg) ? dst : esrc[e0 + i];
      float e = aS[(size_t)s * 4 + h] + advh;
      e = e > 0.f ? e : 0.2f * e;
      float w = __expf(e - mh) * dinv;
      u32x4 p = *(const u32x4*)(HGb + (size_t)s * ldH);
      acc8(acc, w, p);
    }
  }
#pragma unroll
  for (int c = 0; c < 8; c++) s_acc[grp][ch0 + c] = acc[c];
  __syncthreads();

  // ---- epilogue: +bias +linear +ELU, write next-layer bf16 input ----
  const int c4 = tid * 4;
  const u16* lr = HG + (size_t)dst * ldH + 1024 + c4;
  ushort4 u = *(const ushort4*)lr;
  float lv[4] = { bf2f(u.x), bf2f(u.y), bf2f(u.z), bf2f(u.w) };
  ushort4 o;
  float v0 = s_acc[0][c4+0] + s_acc[1][c4+0] + bias[c4+0] + lv[0] + lbias[c4+0]; v0 = v0 > 0.f ? v0 : __expf(v0) - 1.f;
  float v1 = s_acc[0][c4+1] + s_acc[1][c4+1] + bias[c4+1] + lv[1] + lbias[c4+1]; v1 = v1 > 0.f ? v1 : __expf(v1) - 1.f;
  float v2 = s_acc[0][c4+2] + s_acc[1][c4+2] + bias[c4+2] + lv[2] + lbias[c4+2]; v2 = v2 > 0.f ? v2 : __expf(v2) - 1.f;
  float v3 = s_acc[0][c4+3] + s_acc[1][c4+3] + bias[c4+3] + lv[3] + lbias[c4+3]; v3 = v3 > 0.f ? v3 : __expf(v3) - 1.f;
  o.x = f2bf(v0); o.y = f2bf(v1); o.z = f2bf(v2); o.w = f2bf(v3);
  *(ushort4*)(outb + (size_t)dst * 1024 + c4) = o;
}

// ---------------- H=6 FINAL: 384 threads = 2 edge-groups x 3 waves x 8ch ----------------
__global__ __launch_bounds__(384)
void agg6_k(const u16* __restrict__ HG, int ldH,
            const int* __restrict__ rowp, const int* __restrict__ esrc,
            const float* __restrict__ aS, const float* __restrict__ aD,
            const float* __restrict__ bias, const float* __restrict__ lbias,
            float* __restrict__ outf)
{
  constexpr int MAXE = 320;
  __shared__ float s_m[6], s_dinv[6], s_red[36];
  __shared__ float s_ew[MAXE * 6];
  __shared__ int   s_src[MAXE];
  __shared__ float s_acc[2][1536];

  const int dst = blockIdx.x;
  const int tid = threadIdx.x, lane = tid & 63, wv = tid >> 6;   // wv 0..5
  const int e0 = rowp[dst];
  const int deg = rowp[dst + 1] - e0;
  const int nE = deg + 1;
  const bool fits = (nE <= MAXE);

  float adv[6];
#pragma unroll
  for (int h = 0; h < 6; h++) adv[h] = aD[(size_t)dst * 6 + h];

  // ---- P1 ----
  float lm[6];
#pragma unroll
  for (int h = 0; h < 6; h++) lm[h] = -1e30f;
  for (int i = tid; i < nE; i += 384){
    int s = (i == deg) ? dst : esrc[e0 + i];
    if (fits) s_src[i] = s;
#pragma unroll
    for (int h = 0; h < 6; h++){
      float e = aS[(size_t)s * 6 + h] + adv[h];
      e = e > 0.f ? e : 0.2f * e;
      if (fits) s_ew[i * 6 + h] = e;
      lm[h] = fmaxf(lm[h], e);
    }
  }
#pragma unroll
  for (int h = 0; h < 6; h++)
#pragma unroll
    for (int off = 32; off; off >>= 1) lm[h] = fmaxf(lm[h], __shfl_down(lm[h], off));
  if (lane == 0){
#pragma unroll
    for (int h = 0; h < 6; h++) s_red[wv * 6 + h] = lm[h];
  }
  __syncthreads();
  if (tid < 6){
    float m = s_red[tid];
#pragma unroll
    for (int w = 1; w < 6; w++) m = fmaxf(m, s_red[w * 6 + tid]);
    s_m[tid] = m;
  }
  __syncthreads();

  // ---- P2 ----
  float ls[6];
#pragma unroll
  for (int h = 0; h < 6; h++) ls[h] = 0.f;
  for (int i = tid; i < nE; i += 384){
    if (fits){
#pragma unroll
      for (int h = 0; h < 6; h++){
        float w = __expf(s_ew[i * 6 + h] - s_m[h]);
        s_ew[i * 6 + h] = w;
        ls[h] += w;
      }
    } else {
      int s = (i == deg) ? dst : esrc[e0 + i];
#pragma unroll
      for (int h = 0; h < 6; h++){
        float e = aS[(size_t)s * 6 + h] + adv[h];
        e = e > 0.f ? e : 0.2f * e;
        ls[h] += __expf(e - s_m[h]);
      }
    }
  }
#pragma unroll
  for (int h = 0; h < 6; h++)
#pragma unroll
    for (int off = 32; off; off >>= 1) ls[h] += __shfl_down(ls[h], off);
  if (lane == 0){
#pragma unroll
    for (int h = 0; h < 6; h++) s_red[wv * 6 + h] = ls[h];
  }
  __syncthreads();
  if (tid < 6){
    float s = 0.f;
#pragma unroll
    for (int w = 0; w < 6; w++) s += s_red[w * 6 + tid];
    s_dinv[tid] = 1.f / (s + 1e-16f);
  }
  __syncthreads();

  // ---- P3: group = wv/3 edge parity; 3 waves cover 1536 ch at 8ch/lane ----
  const int grp  = wv / 3;
  const int wrow = wv - grp * 3;
  const int ch0  = wrow * 512 + lane * 8;
  const int h    = ch0 >> 8;
  const float dinv = s_dinv[h];
  const float mh   = s_m[h];
  float acc[8] = {};
  const u16* HGb = HG + ch0;

  if (fits){
    int i = grp;
    for (; i + 2 < nE; i += 4){
      int s0 = s_src[i], s1 = s_src[i + 2];
      float w0 = s_ew[i * 6 + h] * dinv;
      float w1 = s_ew[(i + 2) * 6 + h] * dinv;
      u32x4 p0 = *(const u32x4*)(HGb + (size_t)s0 * ldH);
      u32x4 p1 = *(const u32x4*)(HGb + (size_t)s1 * ldH);
      acc8(acc, w0, p0);
      acc8(acc, w1, p1);
    }
    if (i < nE){
      int s0 = s_src[i];
      float w0 = s_ew[i * 6 + h] * dinv;
      u32x4 p0 = *(const u32x4*)(HGb + (size_t)s0 * ldH);
      acc8(acc, w0, p0);
    }
  } else {
    float advh = aD[(size_t)dst * 6 + h];
    for (int i = grp; i < nE; i += 2){
      int s = (i == deg) ? dst : esrc[e0 + i];
      float e = aS[(size_t)s * 6 + h] + advh;
      e = e > 0.f ? e : 0.2f * e;
      float w = __expf(e - mh) * dinv;
      u32x4 p = *(const u32x4*)(HGb + (size_t)s * ldH);
      acc8(acc, w, p);
    }
  }
#pragma unroll
  for (int c = 0; c < 8; c++) s_acc[grp][ch0 + c] = acc[c];
  __syncthreads();

  // ---- epilogue: mean over heads + bias + linear ----
  if (tid < 256){
    int c = tid;
    float v = 0.f;
#pragma unroll
    for (int hh = 0; hh < 6; hh++) v += s_acc[0][hh * 256 + c] + s_acc[1][hh * 256 + c];
    v = v * (1.f / 6.f) + bias[c] + bf2f(HG[(size_t)dst * ldH + 1536 + c]) + lbias[c];
    outf[(size_t)dst * 256 + c] = v;
  }
}

// ---------------- host orchestration ----------------
extern "C" void kernel_launch(void* const* d_in, const int* in_sizes, int n_in,
                              void* d_out, int out_size, void* d_ws, size_t ws_size,
                              hipStream_t stream)
{
  const float* x   = (const float*)d_in[0];
  const int*   ei  = (const int*)  d_in[1];
  const float* W1  = (const float*)d_in[3];
  const float* as1 = (const float*)d_in[4];
  const float* ad1 = (const float*)d_in[5];
  const float* b1  = (const float*)d_in[6];
  const float* lw1 = (const float*)d_in[7];
  const float* lb1 = (const float*)d_in[8];
  const float* W2  = (const float*)d_in[9];
  const float* as2 = (const float*)d_in[10];
  const float* ad2 = (const float*)d_in[11];
  const float* b2  = (const float*)d_in[12];
  const float* lw2 = (const float*)d_in[13];
  const float* lb2 = (const float*)d_in[14];
  const float* W3  = (const float*)d_in[15];
  const float* as3 = (const float*)d_in[16];
  const float* ad3 = (const float*)d_in[17];
  const float* b3  = (const float*)d_in[18];
  const float* lw3 = (const float*)d_in[19];
  const float* lb3 = (const float*)d_in[20];

  char* wp = (char*)d_ws;
  auto nxt = [&](size_t b) -> void* {
    void* p = (void*)wp; wp += (b + 255) & ~(size_t)255; return p;
  };
  u16*  Wt1  = (u16*) nxt((size_t)2048 * 512  * 2);
  u16*  Wt2  = (u16*) nxt((size_t)2048 * 1024 * 2);
  u16*  Wt3  = (u16*) nxt((size_t)1792 * 1024 * 2);
  u16*  Xb   = (u16*) nxt((size_t)M_PAD * 1024 * 2);
  u16*  HG   = (u16*) nxt((size_t)M_PAD * 2048 * 2);
  float* aS  = (float*)nxt((size_t)M_PAD * 6 * 4);
  float* aD  = (float*)nxt((size_t)M_PAD * 6 * 4);
  int*  cnt  = (int*)  nxt((size_t)N_NODES * 4);
  int*  rowp = (int*)  nxt((size_t)(N_NODES + 1) * 4);
  int*  fill = (int*)  nxt((size_t)N_NODES * 4);
  int*  esrc = (int*)  nxt((size_t)E_EDGES * 4);

  // CSR by dst
  hipMemsetAsync(cnt, 0, (size_t)N_NODES * 4, stream);
  hist_k   <<<(E_EDGES + 255) / 256, 256, 0, stream>>>(ei, cnt);
  scan_k   <<<1, 1024, 0, stream>>>(cnt, rowp, fill, N_NODES);
  scatter_k<<<(E_EDGES + 255) / 256, 256, 0, stream>>>(ei, fill, esrc);

  // weights -> K-major bf16 [Wgat | Wlin]
  tcast_all<<<4864, dim3(32, 8), 0, stream>>>(W1, lw1, Wt1, W2, lw2, Wt2, W3, lw3, Wt3);

  // x -> bf16 padded; zero pad rows of the 1024-wide layout
  castx_k<<<M_PAD, 256, 0, stream>>>(x, Xb, N_NODES);
  zpad_k <<<(96 * 1024 + 255) / 256, 256, 0, stream>>>(Xb + (size_t)N_NODES * 1024, 96 * 1024);

  const int MT = M_PAD / 128;   // 157

  // ---- layer 1 ----
  gemm_bf16<<<dim3(2048 / 256, MT), 256, 0, stream>>>(Xb, Wt1, HG, 2048, 512,  as1, ad1, aS, aD, 4);
  agg4_k   <<<N_NODES, 256, 0, stream>>>(HG, 2048, rowp, esrc, aS, aD, b1, lb1, Xb);

  // ---- layer 2 ----
  gemm_bf16<<<dim3(2048 / 256, MT), 256, 0, stream>>>(Xb, Wt2, HG, 2048, 1024, as2, ad2, aS, aD, 4);
  agg4_k   <<<N_NODES, 256, 0, stream>>>(HG, 2048, rowp, esrc, aS, aD, b2, lb2, Xb);

  // ---- layer 3 ----
  gemm_bf16<<<dim3(1792 / 256, MT), 256, 0, stream>>>(Xb, Wt3, HG, 1792, 1024, as3, ad3, aS, aD, 6);
  int outRows = out_size / 256;   // 16384
  agg6_k   <<<outRows, 384, 0, stream>>>(HG, 1792, rowp, esrc, aS, aD, b3, lb3, (float*)d_out);

  (void)in_sizes; (void)n_in; (void)ws_size;
}

// Round 4
// 865.155 us; speedup vs baseline: 1.1122x; 1.0099x over previous
//
#include <hip/hip_runtime.h>

// ---------------- constants (problem-fixed sizes) ----------------
#define N_NODES 20000
#define M_PAD   20096   // 157 * 128
#define E_EDGES 320000

typedef unsigned short u16;
typedef unsigned int   u32;
typedef __attribute__((ext_vector_type(8))) short bf16x8;
typedef __attribute__((ext_vector_type(4))) float f32x4;
typedef __attribute__((ext_vector_type(4))) u32   u32x4;

__device__ __forceinline__ float bf2f(u16 u){
  u32 x = ((u32)u) << 16; float f; __builtin_memcpy(&f, &x, 4); return f;
}
__device__ __forceinline__ u16 f2bf(float f){
  u32 u; __builtin_memcpy(&u, &f, 4);
  u += 0x7fffu + ((u >> 16) & 1u);          // RNE
  return (u16)(u >> 16);
}
__device__ __forceinline__ float lrelu(float x){ return x > 0.f ? x : 0.2f * x; }

__device__ __forceinline__ void gl_lds16(const void* g, void* l){
  __builtin_amdgcn_global_load_lds((const __attribute__((address_space(1))) void*)g,
                                   (__attribute__((address_space(3))) void*)l, 16, 0, 0);
}

__device__ __forceinline__ void acc8(float* acc, float w, u32x4 p){
#pragma unroll
  for (int d = 0; d < 4; d++){
    u32 u = p[d];
    acc[2 * d]     += w * bf2f((u16)(u & 0xffff));
    acc[2 * d + 1] += w * bf2f((u16)(u >> 16));
  }
}

// 24 channels, head boundary at dword index bnd/2 (bnd is even)
__device__ __forceinline__ void acc24(float* acc, float w0, float w1, int bnd,
                                      u32x4 p0, u32x4 p1, u32x4 p2){
  u32 u[12];
  *(u32x4*)(u) = p0; *(u32x4*)(u + 4) = p1; *(u32x4*)(u + 8) = p2;
#pragma unroll
  for (int d = 0; d < 12; d++){
    float w = (2 * d < bnd) ? w0 : w1;
    acc[2 * d]     += w * bf2f((u16)(u[d] & 0xffff));
    acc[2 * d + 1] += w * bf2f((u16)(u[d] >> 16));
  }
}

__device__ __forceinline__ float sel6(const float* a, int h){
  float r = a[0];
  r = (h == 1) ? a[1] : r; r = (h == 2) ? a[2] : r; r = (h == 3) ? a[3] : r;
  r = (h == 4) ? a[4] : r; r = (h == 5) ? a[5] : r;
  return r;
}

// ---------------- CSR build ----------------
__global__ void hist_k(const int* __restrict__ ei, int* __restrict__ cnt){
  int i = blockIdx.x * 256 + threadIdx.x;
  if (i < E_EDGES) atomicAdd(&cnt[ei[E_EDGES + i]], 1);
}

// single-block wave-shuffle scan; also writes the fill[] working copy
__global__ void scan_k(const int* __restrict__ cnt, int* __restrict__ rowp,
                       int* __restrict__ fill, int n){
  __shared__ int wsum[16], wpre[16];
  __shared__ int carry;
  int tid = threadIdx.x, lane = tid & 63, wv = tid >> 6;
  if (tid == 0) carry = 0;
  __syncthreads();
  for (int base = 0; base < n; base += 1024){
    int i = base + tid;
    int v = (i < n) ? cnt[i] : 0;
    int incl = v;
#pragma unroll
    for (int d = 1; d < 64; d <<= 1){
      int t = __shfl_up(incl, d, 64);
      if (lane >= d) incl += t;
    }
    if (lane == 63) wsum[wv] = incl;
    __syncthreads();
    if (tid == 0){
      int s = carry;
#pragma unroll
      for (int w = 0; w < 16; w++){ wpre[w] = s; s += wsum[w]; }
      carry = s;
    }
    __syncthreads();
    if (i < n){ int e = wpre[wv] + incl - v; rowp[i] = e; fill[i] = e; }
  }
  __syncthreads();
  if (tid == 0) rowp[n] = carry;
}

__global__ void scatter_k(const int* __restrict__ ei, int* __restrict__ fill, int* __restrict__ esrc){
  int i = blockIdx.x * 256 + threadIdx.x;
  if (i < E_EDGES){
    int d = ei[E_EDGES + i];
    int p = atomicAdd(&fill[d], 1);
    esrc[p] = ei[i];
  }
}

// ---------------- weight transpose+cast, all 6 jobs in one kernel ----------------
__global__ void tcast_all(const float* __restrict__ W1, const float* __restrict__ lw1, u16* __restrict__ Wt1,
                          const float* __restrict__ W2, const float* __restrict__ lw2, u16* __restrict__ Wt2,
                          const float* __restrict__ W3, const float* __restrict__ lw3, u16* __restrict__ Wt3)
{
  __shared__ float tile[32][33];
  int b = blockIdx.x;
  const float* src; u16* dst; int Nc, n0, ldd;
  if      (b <  512){            src = W1;  Nc = 1024; dst = Wt1; n0 = 0;    ldd = 512;  }
  else if (b < 1024){ b -=  512; src = lw1; Nc = 1024; dst = Wt1; n0 = 1024; ldd = 512;  }
  else if (b < 2048){ b -= 1024; src = W2;  Nc = 1024; dst = Wt2; n0 = 0;    ldd = 1024; }
  else if (b < 3072){ b -= 2048; src = lw2; Nc = 1024; dst = Wt2; n0 = 1024; ldd = 1024; }
  else if (b < 4608){ b -= 3072; src = W3;  Nc = 1536; dst = Wt3; n0 = 0;    ldd = 1024; }
  else              { b -= 4608; src = lw3; Nc = 256;  dst = Wt3; n0 = 1536; ldd = 1024; }
  int gx = Nc / 32;
  int kb = (b / gx) * 32, nb = (b % gx) * 32;
  int tx = threadIdx.x, ty = threadIdx.y;
#pragma unroll
  for (int r = 0; r < 32; r += 8)
    tile[ty + r][tx] = src[(size_t)(kb + ty + r) * Nc + nb + tx];
  __syncthreads();
#pragma unroll
  for (int r = 0; r < 32; r += 8){
    int n = nb + ty + r;
    dst[(size_t)(n0 + n) * ldd + kb + tx] = f2bf(tile[tx][ty + r]);
  }
}

// one row per block, 512 cols, float2 -> packed 2xbf16
__global__ void castx_k(const float* __restrict__ x, u16* __restrict__ o, int realRows){
  int r = blockIdx.x, c = threadIdx.x * 2;
  float2 v = (r < realRows) ? *(const float2*)(x + (size_t)r * 512 + c) : make_float2(0.f, 0.f);
  u32 pk = ((u32)f2bf(v.y) << 16) | (u32)f2bf(v.x);
  *(u32*)(o + (size_t)r * 512 + c) = pk;
}

__global__ void zpad_k(u16* __restrict__ p, int n){
  int i = blockIdx.x * 256 + threadIdx.x; if (i < n) p[i] = 0;
}

// ---------------- bf16 NT GEMM + fused alpha epilogue ----------------
// C[M][N] = A[M][K] * Bt[N][K]^T ; 128x256 tile, BK=32, 256 threads.
// grid: (N/256 fast, M/128). bn tile == one attention head; aS/aD stride 8.
__global__ __launch_bounds__(256, 2)
void gemm_bf16(const u16* __restrict__ A, const u16* __restrict__ Bt, u16* __restrict__ C,
               int N, int K,
               const float* __restrict__ a_s, const float* __restrict__ a_d,
               float* __restrict__ aS, float* __restrict__ aD, int H)
{
  __shared__ __attribute__((aligned(16))) u16 lA[128 * 32];   //  8 KB
  __shared__ __attribute__((aligned(16))) u16 lB[256 * 32];   // 16 KB
  const int tid  = threadIdx.x;
  const int wave = tid >> 6, lane = tid & 63;
  const int bn = blockIdx.x, bm = blockIdx.y;
  const int wm = (wave >> 1) * 64, wn = (wave & 1) * 128;

  const int srow  = wave * 16 + (lane >> 2);
  const int skcol = (lane & 3) * 8;
  const u16* Ag0 = A  + (size_t)(bm * 128 + srow) * K + skcol;
  const u16* Ag1 = Ag0 + (size_t)64 * K;
  const u16* Bg  = Bt + (size_t)(bn * 256 + srow) * K + skcol;
  u16* lA0 = lA + wave * 512; u16* lA1 = lA + 2048 + wave * 512;
  u16* lBw = lB + wave * 512;

  f32x4 acc[4][8] = {};

  for (int k0 = 0; k0 < K; k0 += 32){
    gl_lds16(Ag0 + k0, lA0);
    gl_lds16(Ag1 + k0, lA1);
#pragma unroll
    for (int c = 0; c < 4; c++)
      gl_lds16(Bg + (size_t)(c * 64) * K + k0, lBw + c * 2048);
    __syncthreads();
    const int koff = (lane >> 4) * 8;
    const int rsel = lane & 15;
    bf16x8 af[4], bfr[8];
#pragma unroll
    for (int i = 0; i < 4; i++) af[i]  = *(const bf16x8*)&lA[(wm + i * 16 + rsel) * 32 + koff];
#pragma unroll
    for (int j = 0; j < 8; j++) bfr[j] = *(const bf16x8*)&lB[(wn + j * 16 + rsel) * 32 + koff];
#pragma unroll
    for (int i = 0; i < 4; i++)
#pragma unroll
      for (int j = 0; j < 8; j++)
        acc[i][j] = __builtin_amdgcn_mfma_f32_16x16x32_bf16(af[i], bfr[j], acc[i][j], 0, 0, 0);
    __syncthreads();
  }

  const int r0 = (lane >> 4) * 4, cl = lane & 15;
#pragma unroll
  for (int i = 0; i < 4; i++)
#pragma unroll
    for (int j = 0; j < 8; j++){
      int row = bm * 128 + wm + i * 16 + r0;
      int col = bn * 256 + wn + j * 16 + cl;
      u16* cp = C + (size_t)row * N + col;
#pragma unroll
      for (int r = 0; r < 4; r++) cp[(size_t)r * N] = f2bf(acc[i][j][r]);
    }

  // ---- fused alpha: aS/aD[row*8 + bn] for gat heads ----
  if (bn < H){
    float* fa = (float*)lA;                 // [0..255]=a_s, [256..511]=a_d
    fa[tid]       = a_s[bn * 256 + tid];
    fa[256 + tid] = a_d[bn * 256 + tid];
    __syncthreads();
    float* fb = (float*)lB;                 // parts: s [0..255], d [256..511]
    const int q = lane >> 4;
#pragma unroll
    for (int i = 0; i < 4; i++)
#pragma unroll
      for (int r = 0; r < 4; r++){
        float ps = 0.f, pd = 0.f;
#pragma unroll
        for (int j = 0; j < 8; j++){
          float v = acc[i][j][r];
          int c = wn + j * 16 + cl;
          ps += v * fa[c];
          pd += v * fa[256 + c];
        }
#pragma unroll
        for (int m = 1; m < 16; m <<= 1){
          ps += __shfl_xor(ps, m, 64);
          pd += __shfl_xor(pd, m, 64);
        }
        if (cl == 0){
          int row = wm + i * 16 + q * 4 + r;
          fb[(wave & 1) * 128 + row]       = ps;
          fb[256 + (wave & 1) * 128 + row] = pd;
        }
      }
    __syncthreads();
    if (tid < 128){
      int row = bm * 128 + tid;
      aS[(size_t)row * 8 + bn] = fb[tid] + fb[128 + tid];
      aD[(size_t)row * 8 + bn] = fb[256 + tid] + fb[384 + tid];
    }
  }
}

// ---------------- H=4 wave-per-dst softmax+aggregate ----------------
// 256 threads = 4 waves = 4 dst. Lane i owns edge i (deg<=63 fast path).
__global__ __launch_bounds__(256)
void agg4w_k(const u16* __restrict__ HG, int ldH,
             const int* __restrict__ rowp, const int* __restrict__ esrc,
             const float* __restrict__ aS, const float* __restrict__ aD,
             const float* __restrict__ bias, const float* __restrict__ lbias,
             u16* __restrict__ outb)
{
  __shared__ float s_w[4][256];             // [wave][edge*4+h], normalized weights
  const int tid = threadIdx.x, lane = tid & 63, wv = tid >> 6;
  const int dst = blockIdx.x * 4 + wv;      // grid*4 == 20000 exactly
  const int e0 = rowp[dst];
  const int deg = rowp[dst + 1] - e0;
  const int nE = deg + 1;                   // + implicit self loop (index == deg)
  const float4 adv = *(const float4*)(aD + (size_t)dst * 8);

  // ---- P1: per-lane edge logits + wave max ----
  int myS = dst;
  float ea = -1e30f, eb = -1e30f, ec = -1e30f, ed = -1e30f;
  if (lane < nE){
    myS = (lane == deg) ? dst : esrc[e0 + lane];
    float4 as = *(const float4*)(aS + (size_t)myS * 8);
    ea = lrelu(as.x + adv.x); eb = lrelu(as.y + adv.y);
    ec = lrelu(as.z + adv.z); ed = lrelu(as.w + adv.w);
  }
  float m0 = ea, m1 = eb, m2 = ec, m3 = ed;
  for (int i = lane + 64; i < nE; i += 64){
    int s = (i == deg) ? dst : esrc[e0 + i];
    float4 as = *(const float4*)(aS + (size_t)s * 8);
    m0 = fmaxf(m0, lrelu(as.x + adv.x)); m1 = fmaxf(m1, lrelu(as.y + adv.y));
    m2 = fmaxf(m2, lrelu(as.z + adv.z)); m3 = fmaxf(m3, lrelu(as.w + adv.w));
  }
#pragma unroll
  for (int off = 1; off < 64; off <<= 1){
    m0 = fmaxf(m0, __shfl_xor(m0, off)); m1 = fmaxf(m1, __shfl_xor(m1, off));
    m2 = fmaxf(m2, __shfl_xor(m2, off)); m3 = fmaxf(m3, __shfl_xor(m3, off));
  }

  // ---- P2: exp + wave sum (invalid lanes give exp(-huge)=0) ----
  float w0 = __expf(ea - m0), w1 = __expf(eb - m1);
  float w2 = __expf(ec - m2), w3 = __expf(ed - m3);
  float l0 = w0, l1 = w1, l2 = w2, l3 = w3;
  for (int i = lane + 64; i < nE; i += 64){
    int s = (i == deg) ? dst : esrc[e0 + i];
    float4 as = *(const float4*)(aS + (size_t)s * 8);
    l0 += __expf(lrelu(as.x + adv.x) - m0); l1 += __expf(lrelu(as.y + adv.y) - m1);
    l2 += __expf(lrelu(as.z + adv.z) - m2); l3 += __expf(lrelu(as.w + adv.w) - m3);
  }
#pragma unroll
  for (int off = 1; off < 64; off <<= 1){
    l0 += __shfl_xor(l0, off); l1 += __shfl_xor(l1, off);
    l2 += __shfl_xor(l2, off); l3 += __shfl_xor(l3, off);
  }
  float d0 = 1.f / (l0 + 1e-16f), d1 = 1.f / (l1 + 1e-16f);
  float d2 = 1.f / (l2 + 1e-16f), d3 = 1.f / (l3 + 1e-16f);
  *(float4*)&s_w[wv][lane * 4] = make_float4(w0 * d0, w1 * d1, w2 * d2, w3 * d3);
  __syncthreads();

  // ---- P3: full-row weighted gather, 16 ch (32B) per lane ----
  const int h = lane >> 4;                  // single head per lane (16 | 256)
  const int ch0 = lane * 16;
  const float mh   = (h < 2) ? (h == 0 ? m0 : m1) : (h == 2 ? m2 : m3);
  const float dh   = (h < 2) ? (h == 0 ? d0 : d1) : (h == 2 ? d2 : d3);
  const float advh = (h < 2) ? (h == 0 ? adv.x : adv.y) : (h == 2 ? adv.z : adv.w);
  float acc[16] = {};
  const u16* HGc = HG + ch0;
  const int nF = nE < 64 ? nE : 64;
  int i = 0;
  for (; i + 1 < nF; i += 2){
    int sA = __shfl(myS, i), sB = __shfl(myS, i + 1);
    float wA = s_w[wv][i * 4 + h], wB = s_w[wv][(i + 1) * 4 + h];
    const u16* ra = HGc + (size_t)sA * ldH;
    const u16* rb = HGc + (size_t)sB * ldH;
    u32x4 pa0 = *(const u32x4*)ra, pa1 = *(const u32x4*)(ra + 8);
    u32x4 pb0 = *(const u32x4*)rb, pb1 = *(const u32x4*)(rb + 8);
    acc8(acc, wA, pa0); acc8(acc + 8, wA, pa1);
    acc8(acc, wB, pb0); acc8(acc + 8, wB, pb1);
  }
  if (i < nF){
    int sA = __shfl(myS, i);
    float wA = s_w[wv][i * 4 + h];
    const u16* ra = HGc + (size_t)sA * ldH;
    acc8(acc, wA, *(const u32x4*)ra); acc8(acc + 8, wA, *(const u32x4*)(ra + 8));
  }
  for (int j = 64; j < nE; j++){            // rare high-degree tail
    int s = (j == deg) ? dst : esrc[e0 + j];
    float e = lrelu(aS[(size_t)s * 8 + h] + advh);
    float w = __expf(e - mh) * dh;
    const u16* r = HGc + (size_t)s * ldH;
    acc8(acc, w, *(const u32x4*)r); acc8(acc + 8, w, *(const u32x4*)(r + 8));
  }

  // ---- epilogue: +bias +linear +ELU -> next-layer bf16 input ----
  const u16* lr = HG + (size_t)dst * ldH + 1024 + ch0;
  u32x4 q0 = *(const u32x4*)lr, q1 = *(const u32x4*)(lr + 8);
  float lin[16];
#pragma unroll
  for (int d = 0; d < 4; d++){
    lin[2*d]     = bf2f((u16)(q0[d] & 0xffff)); lin[2*d+1]   = bf2f((u16)(q0[d] >> 16));
    lin[8+2*d]   = bf2f((u16)(q1[d] & 0xffff)); lin[8+2*d+1] = bf2f((u16)(q1[d] >> 16));
  }
  u32 o[8];
#pragma unroll
  for (int d = 0; d < 8; d++){
    float va = acc[2*d]   + bias[ch0 + 2*d]   + lin[2*d]   + lbias[ch0 + 2*d];
    float vb = acc[2*d+1] + bias[ch0 + 2*d+1] + lin[2*d+1] + lbias[ch0 + 2*d+1];
    va = va > 0.f ? va : __expf(va) - 1.f;
    vb = vb > 0.f ? vb : __expf(vb) - 1.f;
    o[d] = ((u32)f2bf(vb) << 16) | (u32)f2bf(va);
  }
  u16* op = outb + (size_t)dst * 1024 + ch0;
  *(u32x4*)op = *(u32x4*)o;
  *(u32x4*)(op + 8) = *(u32x4*)(o + 4);
}

// ---------------- H=6 FINAL wave-per-dst: mean over heads + linear ----------------
__global__ __launch_bounds__(256)
void agg6w_k(const u16* __restrict__ HG, int ldH,
             const int* __restrict__ rowp, const int* __restrict__ esrc,
             const float* __restrict__ aS, const float* __restrict__ aD,
             const float* __restrict__ bias, const float* __restrict__ lbias,
             float* __restrict__ outf)
{
  __shared__ float s_w[4][64 * 6];          // 6 KB
  __shared__ float s_fin[4][1536];          // 24 KB
  const int tid = threadIdx.x, lane = tid & 63, wv = tid >> 6;
  const int dst = blockIdx.x * 4 + wv;      // grid*4 == 16384 exactly
  const int e0 = rowp[dst];
  const int deg = rowp[dst + 1] - e0;
  const int nE = deg + 1;

  const float* advp = aD + (size_t)dst * 8;
  float4 av4 = *(const float4*)advp; float2 av2 = *(const float2*)(advp + 4);
  float adv[6] = { av4.x, av4.y, av4.z, av4.w, av2.x, av2.y };

  // ---- P1 ----
  int myS = dst;
  float e[6];
#pragma unroll
  for (int h = 0; h < 6; h++) e[h] = -1e30f;
  if (lane < nE){
    myS = (lane == deg) ? dst : esrc[e0 + lane];
    float4 a0 = *(const float4*)(aS + (size_t)myS * 8);
    float2 a1 = *(const float2*)(aS + (size_t)myS * 8 + 4);
    e[0] = lrelu(a0.x + adv[0]); e[1] = lrelu(a0.y + adv[1]);
    e[2] = lrelu(a0.z + adv[2]); e[3] = lrelu(a0.w + adv[3]);
    e[4] = lrelu(a1.x + adv[4]); e[5] = lrelu(a1.y + adv[5]);
  }
  float m[6];
#pragma unroll
  for (int h = 0; h < 6; h++) m[h] = e[h];
  for (int i = lane + 64; i < nE; i += 64){
    int s = (i == deg) ? dst : esrc[e0 + i];
    float4 a0 = *(const float4*)(aS + (size_t)s * 8);
    float2 a1 = *(const float2*)(aS + (size_t)s * 8 + 4);
    float t[6] = { a0.x, a0.y, a0.z, a0.w, a1.x, a1.y };
#pragma unroll
    for (int h = 0; h < 6; h++) m[h] = fmaxf(m[h], lrelu(t[h] + adv[h]));
  }
#pragma unroll
  for (int h = 0; h < 6; h++)
#pragma unroll
    for (int off = 1; off < 64; off <<= 1) m[h] = fmaxf(m[h], __shfl_xor(m[h], off));

  // ---- P2 ----
  float w[6], l[6];
#pragma unroll
  for (int h = 0; h < 6; h++){ w[h] = __expf(e[h] - m[h]); l[h] = w[h]; }
  for (int i = lane + 64; i < nE; i += 64){
    int s = (i == deg) ? dst : esrc[e0 + i];
    float4 a0 = *(const float4*)(aS + (size_t)s * 8);
    float2 a1 = *(const float2*)(aS + (size_t)s * 8 + 4);
    float t[6] = { a0.x, a0.y, a0.z, a0.w, a1.x, a1.y };
#pragma unroll
    for (int h = 0; h < 6; h++) l[h] += __expf(lrelu(t[h] + adv[h]) - m[h]);
  }
#pragma unroll
  for (int h = 0; h < 6; h++)
#pragma unroll
    for (int off = 1; off < 64; off <<= 1) l[h] += __shfl_xor(l[h], off);
  float dv[6];
#pragma unroll
  for (int h = 0; h < 6; h++) dv[h] = 1.f / (l[h] + 1e-16f);
  float* swp = &s_w[wv][lane * 6];
  ((float2*)swp)[0] = make_float2(w[0] * dv[0], w[1] * dv[1]);
  ((float2*)swp)[1] = make_float2(w[2] * dv[2], w[3] * dv[3]);
  ((float2*)swp)[2] = make_float2(w[4] * dv[4], w[5] * dv[5]);
  __syncthreads();

  // ---- P3: 24 ch (48B) per lane ----
  const int ch0 = lane * 24;
  const int h0 = ch0 >> 8, h1 = (ch0 + 23) >> 8;
  const int bnd = (h0 + 1) * 256 - ch0;     // even; dwords 2d<bnd use h0
  const float mh0 = sel6(m, h0), mh1 = sel6(m, h1);
  const float dh0 = sel6(dv, h0), dh1 = sel6(dv, h1);
  const float ah0 = sel6(adv, h0), ah1 = sel6(adv, h1);
  float acc[24] = {};
  const u16* HGc = HG + ch0;
  const int nF = nE < 64 ? nE : 64;
  for (int i = 0; i < nF; i++){
    int s = __shfl(myS, i);
    float wA0 = s_w[wv][i * 6 + h0], wA1 = s_w[wv][i * 6 + h1];
    const u16* r = HGc + (size_t)s * ldH;
    acc24(acc, wA0, wA1, bnd,
          *(const u32x4*)r, *(const u32x4*)(r + 8), *(const u32x4*)(r + 16));
  }
  for (int j = 64; j < nE; j++){
    int s = (j == deg) ? dst : esrc[e0 + j];
    float w0 = __expf(lrelu(aS[(size_t)s * 8 + h0] + ah0) - mh0) * dh0;
    float w1 = __expf(lrelu(aS[(size_t)s * 8 + h1] + ah1) - mh1) * dh1;
    const u16* r = HGc + (size_t)s * ldH;
    acc24(acc, w0, w1, bnd,
          *(const u32x4*)r, *(const u32x4*)(r + 8), *(const u32x4*)(r + 16));
  }
#pragma unroll
  for (int d = 0; d < 6; d++)
    *(float4*)&s_fin[wv][ch0 + d * 4] = make_float4(acc[4*d], acc[4*d+1], acc[4*d+2], acc[4*d+3]);
  __syncthreads();

  // ---- epilogue: mean over 6 heads + bias + linear, f32 out ----
  const int c0 = lane * 4;
  float4 sum = make_float4(0.f, 0.f, 0.f, 0.f);
#pragma unroll
  for (int h = 0; h < 6; h++){
    float4 t = *(const float4*)&s_fin[wv][h * 256 + c0];
    sum.x += t.x; sum.y += t.y; sum.z += t.z; sum.w += t.w;
  }
  ushort4 uq = *(const ushort4*)(HG + (size_t)dst * ldH + 1536 + c0);
  float4 bv = *(const float4*)(bias + c0);
  float4 lb = *(const float4*)(lbias + c0);
  float4 o;
  o.x = sum.x * (1.f/6.f) + bv.x + bf2f(uq.x) + lb.x;
  o.y = sum.y * (1.f/6.f) + bv.y + bf2f(uq.y) + lb.y;
  o.z = sum.z * (1.f/6.f) + bv.z + bf2f(uq.z) + lb.z;
  o.w = sum.w * (1.f/6.f) + bv.w + bf2f(uq.w) + lb.w;
  *(float4*)(outf + (size_t)dst * 256 + c0) = o;
}

// ---------------- host orchestration ----------------
extern "C" void kernel_launch(void* const* d_in, const int* in_sizes, int n_in,
                              void* d_out, int out_size, void* d_ws, size_t ws_size,
                              hipStream_t stream)
{
  const float* x   = (const float*)d_in[0];
  const int*   ei  = (const int*)  d_in[1];
  const float* W1  = (const float*)d_in[3];
  const float* as1 = (const float*)d_in[4];
  const float* ad1 = (const float*)d_in[5];
  const float* b1  = (const float*)d_in[6];
  const float* lw1 = (const float*)d_in[7];
  const float* lb1 = (const float*)d_in[8];
  const float* W2  = (const float*)d_in[9];
  const float* as2 = (const float*)d_in[10];
  const float* ad2 = (const float*)d_in[11];
  const float* b2  = (const float*)d_in[12];
  const float* lb2p= (const float*)d_in[14];
  const float* lw2 = (const float*)d_in[13];
  const float* W3  = (const float*)d_in[15];
  const float* as3 = (const float*)d_in[16];
  const float* ad3 = (const float*)d_in[17];
  const float* b3  = (const float*)d_in[18];
  const float* lw3 = (const float*)d_in[19];
  const float* lb3 = (const float*)d_in[20];

  char* wp = (char*)d_ws;
  auto nxt = [&](size_t b) -> void* {
    void* p = (void*)wp; wp += (b + 255) & ~(size_t)255; return p;
  };
  u16*  Wt1  = (u16*) nxt((size_t)2048 * 512  * 2);
  u16*  Wt2  = (u16*) nxt((size_t)2048 * 1024 * 2);
  u16*  Wt3  = (u16*) nxt((size_t)1792 * 1024 * 2);
  u16*  Xb   = (u16*) nxt((size_t)M_PAD * 1024 * 2);
  u16*  HG   = (u16*) nxt((size_t)M_PAD * 2048 * 2);
  float* aS  = (float*)nxt((size_t)M_PAD * 8 * 4);
  float* aD  = (float*)nxt((size_t)M_PAD * 8 * 4);
  int*  cnt  = (int*)  nxt((size_t)N_NODES * 4);
  int*  rowp = (int*)  nxt((size_t)(N_NODES + 1) * 4);
  int*  fill = (int*)  nxt((size_t)N_NODES * 4);
  int*  esrc = (int*)  nxt((size_t)E_EDGES * 4);

  // CSR by dst
  hipMemsetAsync(cnt, 0, (size_t)N_NODES * 4, stream);
  hist_k   <<<(E_EDGES + 255) / 256, 256, 0, stream>>>(ei, cnt);
  scan_k   <<<1, 1024, 0, stream>>>(cnt, rowp, fill, N_NODES);
  scatter_k<<<(E_EDGES + 255) / 256, 256, 0, stream>>>(ei, fill, esrc);

  // weights -> K-major bf16 [Wgat | Wlin]
  tcast_all<<<4864, dim3(32, 8), 0, stream>>>(W1, lw1, Wt1, W2, lw2, Wt2, W3, lw3, Wt3);

  // x -> bf16 padded; zero pad rows of the 1024-wide layout
  castx_k<<<M_PAD, 256, 0, stream>>>(x, Xb, N_NODES);
  zpad_k <<<(96 * 1024 + 255) / 256, 256, 0, stream>>>(Xb + (size_t)N_NODES * 1024, 96 * 1024);

  const int MT = M_PAD / 128;   // 157

  // ---- layer 1 ----
  gemm_bf16<<<dim3(2048 / 256, MT), 256, 0, stream>>>(Xb, Wt1, HG, 2048, 512,  as1, ad1, aS, aD, 4);
  agg4w_k  <<<N_NODES / 4, 256, 0, stream>>>(HG, 2048, rowp, esrc, aS, aD, b1, lb1, Xb);

  // ---- layer 2 ----
  gemm_bf16<<<dim3(2048 / 256, MT), 256, 0, stream>>>(Xb, Wt2, HG, 2048, 1024, as2, ad2, aS, aD, 4);
  agg4w_k  <<<N_NODES / 4, 256, 0, stream>>>(HG, 2048, rowp, esrc, aS, aD, b2, lb2p, Xb);

  // ---- layer 3 ----
  gemm_bf16<<<dim3(1792 / 256, MT), 256, 0, stream>>>(Xb, Wt3, HG, 1792, 1024, as3, ad3, aS, aD, 6);
  int outRows = out_size / 256;   // 16384
  agg6w_k  <<<outRows / 4, 256, 0, stream>>>(HG, 1792, rowp, esrc, aS, aD, b3, lb3, (float*)d_out);

  (void)in_sizes; (void)n_in; (void)ws_size;
}

// Round 5
// 840.853 us; speedup vs baseline: 1.1443x; 1.0289x over previous
//
#include <hip/hip_runtime.h>

// ---------------- constants (problem-fixed sizes) ----------------
#define N_NODES 20000
#define M_PAD   20096   // 157 * 128
#define E_EDGES 320000

typedef unsigned short u16;
typedef unsigned int   u32;
typedef __attribute__((ext_vector_type(8))) short bf16x8;
typedef __attribute__((ext_vector_type(4))) float f32x4;
typedef __attribute__((ext_vector_type(4))) u32   u32x4;

__device__ __forceinline__ float bf2f(u16 u){
  u32 x = ((u32)u) << 16; float f; __builtin_memcpy(&f, &x, 4); return f;
}
__device__ __forceinline__ u16 f2bf(float f){
  u32 u; __builtin_memcpy(&u, &f, 4);
  u += 0x7fffu + ((u >> 16) & 1u);          // RNE
  return (u16)(u >> 16);
}
__device__ __forceinline__ float lrelu(float x){ return x > 0.f ? x : 0.2f * x; }

__device__ __forceinline__ void gl_lds16(const void* g, void* l){
  __builtin_amdgcn_global_load_lds((const __attribute__((address_space(1))) void*)g,
                                   (__attribute__((address_space(3))) void*)l, 16, 0, 0);
}

__device__ __forceinline__ void acc8(float* acc, float w, u32x4 p){
#pragma unroll
  for (int d = 0; d < 4; d++){
    u32 u = p[d];
    acc[2 * d]     += w * bf2f((u16)(u & 0xffff));
    acc[2 * d + 1] += w * bf2f((u16)(u >> 16));
  }
}

// ---------------- CSR build ----------------
__global__ void hist_k(const int* __restrict__ ei, int* __restrict__ cnt){
  int i = blockIdx.x * 256 + threadIdx.x;
  if (i < E_EDGES) atomicAdd(&cnt[ei[E_EDGES + i]], 1);
}

// single-block wave-shuffle scan; also writes the fill[] working copy
__global__ void scan_k(const int* __restrict__ cnt, int* __restrict__ rowp,
                       int* __restrict__ fill, int n){
  __shared__ int wsum[16], wpre[16];
  __shared__ int carry;
  int tid = threadIdx.x, lane = tid & 63, wv = tid >> 6;
  if (tid == 0) carry = 0;
  __syncthreads();
  for (int base = 0; base < n; base += 1024){
    int i = base + tid;
    int v = (i < n) ? cnt[i] : 0;
    int incl = v;
#pragma unroll
    for (int d = 1; d < 64; d <<= 1){
      int t = __shfl_up(incl, d, 64);
      if (lane >= d) incl += t;
    }
    if (lane == 63) wsum[wv] = incl;
    __syncthreads();
    if (tid == 0){
      int s = carry;
#pragma unroll
      for (int w = 0; w < 16; w++){ wpre[w] = s; s += wsum[w]; }
      carry = s;
    }
    __syncthreads();
    if (i < n){ int e = wpre[wv] + incl - v; rowp[i] = e; fill[i] = e; }
  }
  __syncthreads();
  if (tid == 0) rowp[n] = carry;
}

__global__ void scatter_k(const int* __restrict__ ei, int* __restrict__ fill, int* __restrict__ esrc){
  int i = blockIdx.x * 256 + threadIdx.x;
  if (i < E_EDGES){
    int d = ei[E_EDGES + i];
    int p = atomicAdd(&fill[d], 1);
    esrc[p] = ei[i];
  }
}

// ---------------- weight transpose+cast, all 6 jobs in one kernel ----------------
__global__ void tcast_all(const float* __restrict__ W1, const float* __restrict__ lw1, u16* __restrict__ Wt1,
                          const float* __restrict__ W2, const float* __restrict__ lw2, u16* __restrict__ Wt2,
                          const float* __restrict__ W3, const float* __restrict__ lw3, u16* __restrict__ Wt3)
{
  __shared__ float tile[32][33];
  int b = blockIdx.x;
  const float* src; u16* dst; int Nc, n0, ldd;
  if      (b <  512){            src = W1;  Nc = 1024; dst = Wt1; n0 = 0;    ldd = 512;  }
  else if (b < 1024){ b -=  512; src = lw1; Nc = 1024; dst = Wt1; n0 = 1024; ldd = 512;  }
  else if (b < 2048){ b -= 1024; src = W2;  Nc = 1024; dst = Wt2; n0 = 0;    ldd = 1024; }
  else if (b < 3072){ b -= 2048; src = lw2; Nc = 1024; dst = Wt2; n0 = 1024; ldd = 1024; }
  else if (b < 4608){ b -= 3072; src = W3;  Nc = 1536; dst = Wt3; n0 = 0;    ldd = 1024; }
  else              { b -= 4608; src = lw3; Nc = 256;  dst = Wt3; n0 = 1536; ldd = 1024; }
  int gx = Nc / 32;
  int kb = (b / gx) * 32, nb = (b % gx) * 32;
  int tx = threadIdx.x, ty = threadIdx.y;
#pragma unroll
  for (int r = 0; r < 32; r += 8)
    tile[ty + r][tx] = src[(size_t)(kb + ty + r) * Nc + nb + tx];
  __syncthreads();
#pragma unroll
  for (int r = 0; r < 32; r += 8){
    int n = nb + ty + r;
    dst[(size_t)(n0 + n) * ldd + kb + tx] = f2bf(tile[tx][ty + r]);
  }
}

// one row per block, 512 cols, float2 -> packed 2xbf16
__global__ void castx_k(const float* __restrict__ x, u16* __restrict__ o, int realRows){
  int r = blockIdx.x, c = threadIdx.x * 2;
  float2 v = (r < realRows) ? *(const float2*)(x + (size_t)r * 512 + c) : make_float2(0.f, 0.f);
  u32 pk = ((u32)f2bf(v.y) << 16) | (u32)f2bf(v.x);
  *(u32*)(o + (size_t)r * 512 + c) = pk;
}

__global__ void zpad_k(u16* __restrict__ p, int n){
  int i = blockIdx.x * 256 + threadIdx.x; if (i < n) p[i] = 0;
}

// ---------------- bf16 NT GEMM + fused alpha epilogue ----------------
// C[M][N] = A[M][K] * Bt[N][K]^T ; 128x256 tile, BK=32, 256 threads.
// grid: (N/256 fast, M/128). bn tile == one attention head; aS/aD stride 8.
__global__ __launch_bounds__(256, 2)
void gemm_bf16(const u16* __restrict__ A, const u16* __restrict__ Bt, u16* __restrict__ C,
               int N, int K,
               const float* __restrict__ a_s, const float* __restrict__ a_d,
               float* __restrict__ aS, float* __restrict__ aD, int H)
{
  __shared__ __attribute__((aligned(16))) u16 lA[128 * 32];   //  8 KB
  __shared__ __attribute__((aligned(16))) u16 lB[256 * 32];   // 16 KB
  const int tid  = threadIdx.x;
  const int wave = tid >> 6, lane = tid & 63;
  const int bn = blockIdx.x, bm = blockIdx.y;
  const int wm = (wave >> 1) * 64, wn = (wave & 1) * 128;

  const int srow  = wave * 16 + (lane >> 2);
  const int skcol = (lane & 3) * 8;
  const u16* Ag0 = A  + (size_t)(bm * 128 + srow) * K + skcol;
  const u16* Ag1 = Ag0 + (size_t)64 * K;
  const u16* Bg  = Bt + (size_t)(bn * 256 + srow) * K + skcol;
  u16* lA0 = lA + wave * 512; u16* lA1 = lA + 2048 + wave * 512;
  u16* lBw = lB + wave * 512;

  f32x4 acc[4][8] = {};

  for (int k0 = 0; k0 < K; k0 += 32){
    gl_lds16(Ag0 + k0, lA0);
    gl_lds16(Ag1 + k0, lA1);
#pragma unroll
    for (int c = 0; c < 4; c++)
      gl_lds16(Bg + (size_t)(c * 64) * K + k0, lBw + c * 2048);
    __syncthreads();
    const int koff = (lane >> 4) * 8;
    const int rsel = lane & 15;
    bf16x8 af[4], bfr[8];
#pragma unroll
    for (int i = 0; i < 4; i++) af[i]  = *(const bf16x8*)&lA[(wm + i * 16 + rsel) * 32 + koff];
#pragma unroll
    for (int j = 0; j < 8; j++) bfr[j] = *(const bf16x8*)&lB[(wn + j * 16 + rsel) * 32 + koff];
#pragma unroll
    for (int i = 0; i < 4; i++)
#pragma unroll
      for (int j = 0; j < 8; j++)
        acc[i][j] = __builtin_amdgcn_mfma_f32_16x16x32_bf16(af[i], bfr[j], acc[i][j], 0, 0, 0);
    __syncthreads();
  }

  const int r0 = (lane >> 4) * 4, cl = lane & 15;
#pragma unroll
  for (int i = 0; i < 4; i++)
#pragma unroll
    for (int j = 0; j < 8; j++){
      int row = bm * 128 + wm + i * 16 + r0;
      int col = bn * 256 + wn + j * 16 + cl;
      u16* cp = C + (size_t)row * N + col;
#pragma unroll
      for (int r = 0; r < 4; r++) cp[(size_t)r * N] = f2bf(acc[i][j][r]);
    }

  // ---- fused alpha: aS/aD[row*8 + bn] for gat heads ----
  if (bn < H){
    float* fa = (float*)lA;                 // [0..255]=a_s, [256..511]=a_d
    fa[tid]       = a_s[bn * 256 + tid];
    fa[256 + tid] = a_d[bn * 256 + tid];
    __syncthreads();
    float* fb = (float*)lB;                 // parts: s [0..255], d [256..511]
    const int q = lane >> 4;
#pragma unroll
    for (int i = 0; i < 4; i++)
#pragma unroll
      for (int r = 0; r < 4; r++){
        float ps = 0.f, pd = 0.f;
#pragma unroll
        for (int j = 0; j < 8; j++){
          float v = acc[i][j][r];
          int c = wn + j * 16 + cl;
          ps += v * fa[c];
          pd += v * fa[256 + c];
        }
#pragma unroll
        for (int m = 1; m < 16; m <<= 1){
          ps += __shfl_xor(ps, m, 64);
          pd += __shfl_xor(pd, m, 64);
        }
        if (cl == 0){
          int row = wm + i * 16 + q * 4 + r;
          fb[(wave & 1) * 128 + row]       = ps;
          fb[256 + (wave & 1) * 128 + row] = pd;
        }
      }
    __syncthreads();
    if (tid < 128){
      int row = bm * 128 + tid;
      aS[(size_t)row * 8 + bn] = fb[tid] + fb[128 + tid];
      aD[(size_t)row * 8 + bn] = fb[256 + tid] + fb[384 + tid];
    }
  }
}

// ---------------- H=4 wave-per-dst softmax+aggregate ----------------
// 256 threads = 4 waves = 4 dst. Lane i owns edge i (deg<=63 fast path).
__global__ __launch_bounds__(256)
void agg4w_k(const u16* __restrict__ HG, int ldH,
             const int* __restrict__ rowp, const int* __restrict__ esrc,
             const float* __restrict__ aS, const float* __restrict__ aD,
             const float* __restrict__ bias, const float* __restrict__ lbias,
             u16* __restrict__ outb)
{
  __shared__ float s_w[4][256];             // [wave][edge*4+h], normalized weights
  const int tid = threadIdx.x, lane = tid & 63, wv = tid >> 6;
  const int dst = blockIdx.x * 4 + wv;      // grid*4 == 20000 exactly
  const int e0 = rowp[dst];
  const int deg = rowp[dst + 1] - e0;
  const int nE = deg + 1;                   // + implicit self loop (index == deg)
  const float4 adv = *(const float4*)(aD + (size_t)dst * 8);

  // ---- P1: per-lane edge logits + wave max ----
  int myS = dst;
  float ea = -1e30f, eb = -1e30f, ec = -1e30f, ed = -1e30f;
  if (lane < nE){
    myS = (lane == deg) ? dst : esrc[e0 + lane];
    float4 as = *(const float4*)(aS + (size_t)myS * 8);
    ea = lrelu(as.x + adv.x); eb = lrelu(as.y + adv.y);
    ec = lrelu(as.z + adv.z); ed = lrelu(as.w + adv.w);
  }
  float m0 = ea, m1 = eb, m2 = ec, m3 = ed;
  for (int i = lane + 64; i < nE; i += 64){
    int s = (i == deg) ? dst : esrc[e0 + i];
    float4 as = *(const float4*)(aS + (size_t)s * 8);
    m0 = fmaxf(m0, lrelu(as.x + adv.x)); m1 = fmaxf(m1, lrelu(as.y + adv.y));
    m2 = fmaxf(m2, lrelu(as.z + adv.z)); m3 = fmaxf(m3, lrelu(as.w + adv.w));
  }
#pragma unroll
  for (int off = 1; off < 64; off <<= 1){
    m0 = fmaxf(m0, __shfl_xor(m0, off)); m1 = fmaxf(m1, __shfl_xor(m1, off));
    m2 = fmaxf(m2, __shfl_xor(m2, off)); m3 = fmaxf(m3, __shfl_xor(m3, off));
  }

  // ---- P2: exp + wave sum (invalid lanes give exp(-huge)=0) ----
  float w0 = __expf(ea - m0), w1 = __expf(eb - m1);
  float w2 = __expf(ec - m2), w3 = __expf(ed - m3);
  float l0 = w0, l1 = w1, l2 = w2, l3 = w3;
  for (int i = lane + 64; i < nE; i += 64){
    int s = (i == deg) ? dst : esrc[e0 + i];
    float4 as = *(const float4*)(aS + (size_t)s * 8);
    l0 += __expf(lrelu(as.x + adv.x) - m0); l1 += __expf(lrelu(as.y + adv.y) - m1);
    l2 += __expf(lrelu(as.z + adv.z) - m2); l3 += __expf(lrelu(as.w + adv.w) - m3);
  }
#pragma unroll
  for (int off = 1; off < 64; off <<= 1){
    l0 += __shfl_xor(l0, off); l1 += __shfl_xor(l1, off);
    l2 += __shfl_xor(l2, off); l3 += __shfl_xor(l3, off);
  }
  float d0 = 1.f / (l0 + 1e-16f), d1 = 1.f / (l1 + 1e-16f);
  float d2 = 1.f / (l2 + 1e-16f), d3 = 1.f / (l3 + 1e-16f);
  *(float4*)&s_w[wv][lane * 4] = make_float4(w0 * d0, w1 * d1, w2 * d2, w3 * d3);
  __syncthreads();

  // ---- P3: full-row weighted gather, 16 ch (32B) per lane, 4-edge unroll ----
  const int h = lane >> 4;                  // single head per lane (16 | 256)
  const int ch0 = lane * 16;
  const float mh   = (h < 2) ? (h == 0 ? m0 : m1) : (h == 2 ? m2 : m3);
  const float dh   = (h < 2) ? (h == 0 ? d0 : d1) : (h == 2 ? d2 : d3);
  const float advh = (h < 2) ? (h == 0 ? adv.x : adv.y) : (h == 2 ? adv.z : adv.w);
  float acc[16] = {};
  const u16* HGc = HG + ch0;
  const int nF = nE < 64 ? nE : 64;
  int i = 0;
  for (; i + 3 < nF; i += 4){
    int sA = __shfl(myS, i),     sB = __shfl(myS, i + 1);
    int sC = __shfl(myS, i + 2), sD = __shfl(myS, i + 3);
    float wA = s_w[wv][i * 4 + h],       wB = s_w[wv][(i + 1) * 4 + h];
    float wC = s_w[wv][(i + 2) * 4 + h], wD = s_w[wv][(i + 3) * 4 + h];
    const u16* ra = HGc + (size_t)sA * ldH;
    const u16* rb = HGc + (size_t)sB * ldH;
    const u16* rc = HGc + (size_t)sC * ldH;
    const u16* rd = HGc + (size_t)sD * ldH;
    u32x4 pa0 = *(const u32x4*)ra, pa1 = *(const u32x4*)(ra + 8);
    u32x4 pb0 = *(const u32x4*)rb, pb1 = *(const u32x4*)(rb + 8);
    u32x4 pc0 = *(const u32x4*)rc, pc1 = *(const u32x4*)(rc + 8);
    u32x4 pd0 = *(const u32x4*)rd, pd1 = *(const u32x4*)(rd + 8);
    acc8(acc, wA, pa0); acc8(acc + 8, wA, pa1);
    acc8(acc, wB, pb0); acc8(acc + 8, wB, pb1);
    acc8(acc, wC, pc0); acc8(acc + 8, wC, pc1);
    acc8(acc, wD, pd0); acc8(acc + 8, wD, pd1);
  }
  for (; i < nF; i++){
    int sA = __shfl(myS, i);
    float wA = s_w[wv][i * 4 + h];
    const u16* ra = HGc + (size_t)sA * ldH;
    acc8(acc, wA, *(const u32x4*)ra); acc8(acc + 8, wA, *(const u32x4*)(ra + 8));
  }
  for (int j = 64; j < nE; j++){            // rare high-degree tail
    int s = (j == deg) ? dst : esrc[e0 + j];
    float e = lrelu(aS[(size_t)s * 8 + h] + advh);
    float w = __expf(e - mh) * dh;
    const u16* r = HGc + (size_t)s * ldH;
    acc8(acc, w, *(const u32x4*)r); acc8(acc + 8, w, *(const u32x4*)(r + 8));
  }

  // ---- epilogue: +bias +linear +ELU -> next-layer bf16 input ----
  const u16* lr = HG + (size_t)dst * ldH + 1024 + ch0;
  u32x4 q0 = *(const u32x4*)lr, q1 = *(const u32x4*)(lr + 8);
  float lin[16];
#pragma unroll
  for (int d = 0; d < 4; d++){
    lin[2*d]     = bf2f((u16)(q0[d] & 0xffff)); lin[2*d+1]   = bf2f((u16)(q0[d] >> 16));
    lin[8+2*d]   = bf2f((u16)(q1[d] & 0xffff)); lin[8+2*d+1] = bf2f((u16)(q1[d] >> 16));
  }
  u32 o[8];
#pragma unroll
  for (int d = 0; d < 8; d++){
    float va = acc[2*d]   + bias[ch0 + 2*d]   + lin[2*d]   + lbias[ch0 + 2*d];
    float vb = acc[2*d+1] + bias[ch0 + 2*d+1] + lin[2*d+1] + lbias[ch0 + 2*d+1];
    va = va > 0.f ? va : __expf(va) - 1.f;
    vb = vb > 0.f ? vb : __expf(vb) - 1.f;
    o[d] = ((u32)f2bf(vb) << 16) | (u32)f2bf(va);
  }
  u16* op = outb + (size_t)dst * 1024 + ch0;
  *(u32x4*)op = *(u32x4*)o;
  *(u32x4*)(op + 8) = *(u32x4*)(o + 4);
}

// ---------------- H=6 FINAL wave-per-dst, head-mean folded into weights ----------------
// Half-wave = edge parity; lane owns 8 OUTPUT channels; acc = sum_h (w/6)*H.
__global__ __launch_bounds__(256)
void agg6w_k(const u16* __restrict__ HG, int ldH,
             const int* __restrict__ rowp, const int* __restrict__ esrc,
             const float* __restrict__ aS, const float* __restrict__ aD,
             const float* __restrict__ bias, const float* __restrict__ lbias,
             float* __restrict__ outf)
{
  __shared__ float s_w[4][64 * 6];          // 6 KB: w_norm/6 per edge x head
  const int tid = threadIdx.x, lane = tid & 63, wv = tid >> 6;
  const int dst = blockIdx.x * 4 + wv;      // grid*4 == 16384 exactly
  const int e0 = rowp[dst];
  const int deg = rowp[dst + 1] - e0;
  const int nE = deg + 1;

  const float* advp = aD + (size_t)dst * 8;
  float4 av4 = *(const float4*)advp; float2 av2 = *(const float2*)(advp + 4);
  float adv[6] = { av4.x, av4.y, av4.z, av4.w, av2.x, av2.y };

  // ---- P1: per-lane logits + wave max ----
  int myS = dst;
  float e[6];
#pragma unroll
  for (int h = 0; h < 6; h++) e[h] = -1e30f;
  if (lane < nE){
    myS = (lane == deg) ? dst : esrc[e0 + lane];
    float4 a0 = *(const float4*)(aS + (size_t)myS * 8);
    float2 a1 = *(const float2*)(aS + (size_t)myS * 8 + 4);
    e[0] = lrelu(a0.x + adv[0]); e[1] = lrelu(a0.y + adv[1]);
    e[2] = lrelu(a0.z + adv[2]); e[3] = lrelu(a0.w + adv[3]);
    e[4] = lrelu(a1.x + adv[4]); e[5] = lrelu(a1.y + adv[5]);
  }
  float m[6];
#pragma unroll
  for (int h = 0; h < 6; h++) m[h] = e[h];
  for (int i = lane + 64; i < nE; i += 64){
    int s = (i == deg) ? dst : esrc[e0 + i];
    float4 a0 = *(const float4*)(aS + (size_t)s * 8);
    float2 a1 = *(const float2*)(aS + (size_t)s * 8 + 4);
    float t[6] = { a0.x, a0.y, a0.z, a0.w, a1.x, a1.y };
#pragma unroll
    for (int h = 0; h < 6; h++) m[h] = fmaxf(m[h], lrelu(t[h] + adv[h]));
  }
#pragma unroll
  for (int h = 0; h < 6; h++)
#pragma unroll
    for (int off = 1; off < 64; off <<= 1) m[h] = fmaxf(m[h], __shfl_xor(m[h], off));

  // ---- P2: exp + wave sum; store w_norm * (1/6) ----
  float w[6], l[6];
#pragma unroll
  for (int h = 0; h < 6; h++){ w[h] = __expf(e[h] - m[h]); l[h] = w[h]; }
  for (int i = lane + 64; i < nE; i += 64){
    int s = (i == deg) ? dst : esrc[e0 + i];
    float4 a0 = *(const float4*)(aS + (size_t)s * 8);
    float2 a1 = *(const float2*)(aS + (size_t)s * 8 + 4);
    float t[6] = { a0.x, a0.y, a0.z, a0.w, a1.x, a1.y };
#pragma unroll
    for (int h = 0; h < 6; h++) l[h] += __expf(lrelu(t[h] + adv[h]) - m[h]);
  }
#pragma unroll
  for (int h = 0; h < 6; h++)
#pragma unroll
    for (int off = 1; off < 64; off <<= 1) l[h] += __shfl_xor(l[h], off);
  float dv[6];
#pragma unroll
  for (int h = 0; h < 6; h++) dv[h] = (1.f / 6.f) / (l[h] + 1e-16f);
  float* swp = &s_w[wv][lane * 6];
  ((float2*)swp)[0] = make_float2(w[0] * dv[0], w[1] * dv[1]);
  ((float2*)swp)[1] = make_float2(w[2] * dv[2], w[3] * dv[3]);
  ((float2*)swp)[2] = make_float2(w[4] * dv[4], w[5] * dv[5]);
  __syncthreads();

  // ---- P3: half-wave edge parity, 8 output ch/lane, 6 heads x dwordx4 ----
  const int li = lane & 31, half = lane >> 5;
  const int ch0 = li * 8;
  float acc[8] = {};
  const u16* HGc = HG + ch0;
  const int nF = nE < 64 ? nE : 64;
  for (int i = half; i < nF; i += 2){       // weights are 0 for i >= nE
    int s = __shfl(myS, i);
    const u16* r = HGc + (size_t)s * ldH;
    const float* wp6 = &s_w[wv][i * 6];
#pragma unroll
    for (int h = 0; h < 6; h++){
      u32x4 p = *(const u32x4*)(r + h * 256);
      acc8(acc, wp6[h], p);
    }
  }
  for (int j = 64 + half; j < nE; j += 2){  // rare high-degree tail
    int s = (j == deg) ? dst : esrc[e0 + j];
    float4 a0 = *(const float4*)(aS + (size_t)s * 8);
    float2 a1 = *(const float2*)(aS + (size_t)s * 8 + 4);
    float t[6] = { a0.x, a0.y, a0.z, a0.w, a1.x, a1.y };
    const u16* r = HGc + (size_t)s * ldH;
#pragma unroll
    for (int h = 0; h < 6; h++){
      float wt = __expf(lrelu(t[h] + adv[h]) - m[h]) * dv[h];
      u32x4 p = *(const u32x4*)(r + h * 256);
      acc8(acc, wt, p);
    }
  }
#pragma unroll
  for (int c = 0; c < 8; c++) acc[c] += __shfl_xor(acc[c], 32);

  // ---- epilogue (lanes 0..31): + bias + linear + lbias, f32 out ----
  if (lane < 32){
    u32x4 q = *(const u32x4*)(HG + (size_t)dst * ldH + 1536 + ch0);
    float lin[8];
#pragma unroll
    for (int d = 0; d < 4; d++){
      lin[2*d]   = bf2f((u16)(q[d] & 0xffff));
      lin[2*d+1] = bf2f((u16)(q[d] >> 16));
    }
    float4 b0 = *(const float4*)(bias + ch0),  b1 = *(const float4*)(bias + ch0 + 4);
    float4 c0 = *(const float4*)(lbias + ch0), c1 = *(const float4*)(lbias + ch0 + 4);
    float4 o0, o1;
    o0.x = acc[0] + b0.x + lin[0] + c0.x; o0.y = acc[1] + b0.y + lin[1] + c0.y;
    o0.z = acc[2] + b0.z + lin[2] + c0.z; o0.w = acc[3] + b0.w + lin[3] + c0.w;
    o1.x = acc[4] + b1.x + lin[4] + c1.x; o1.y = acc[5] + b1.y + lin[5] + c1.y;
    o1.z = acc[6] + b1.z + lin[6] + c1.z; o1.w = acc[7] + b1.w + lin[7] + c1.w;
    float* op = outf + (size_t)dst * 256 + ch0;
    *(float4*)op = o0;
    *(float4*)(op + 4) = o1;
  }
}

// ---------------- host orchestration ----------------
extern "C" void kernel_launch(void* const* d_in, const int* in_sizes, int n_in,
                              void* d_out, int out_size, void* d_ws, size_t ws_size,
                              hipStream_t stream)
{
  const float* x   = (const float*)d_in[0];
  const int*   ei  = (const int*)  d_in[1];
  const float* W1  = (const float*)d_in[3];
  const float* as1 = (const float*)d_in[4];
  const float* ad1 = (const float*)d_in[5];
  const float* b1  = (const float*)d_in[6];
  const float* lw1 = (const float*)d_in[7];
  const float* lb1 = (const float*)d_in[8];
  const float* W2  = (const float*)d_in[9];
  const float* as2 = (const float*)d_in[10];
  const float* ad2 = (const float*)d_in[11];
  const float* b2  = (const float*)d_in[12];
  const float* lw2 = (const float*)d_in[13];
  const float* lb2 = (const float*)d_in[14];
  const float* W3  = (const float*)d_in[15];
  const float* as3 = (const float*)d_in[16];
  const float* ad3 = (const float*)d_in[17];
  const float* b3  = (const float*)d_in[18];
  const float* lw3 = (const float*)d_in[19];
  const float* lb3 = (const float*)d_in[20];

  char* wp = (char*)d_ws;
  auto nxt = [&](size_t b) -> void* {
    void* p = (void*)wp; wp += (b + 255) & ~(size_t)255; return p;
  };
  u16*  Wt1  = (u16*) nxt((size_t)2048 * 512  * 2);
  u16*  Wt2  = (u16*) nxt((size_t)2048 * 1024 * 2);
  u16*  Wt3  = (u16*) nxt((size_t)1792 * 1024 * 2);
  u16*  Xb   = (u16*) nxt((size_t)M_PAD * 1024 * 2);
  u16*  HG   = (u16*) nxt((size_t)M_PAD * 2048 * 2);
  float* aS  = (float*)nxt((size_t)M_PAD * 8 * 4);
  float* aD  = (float*)nxt((size_t)M_PAD * 8 * 4);
  int*  cnt  = (int*)  nxt((size_t)N_NODES * 4);
  int*  rowp = (int*)  nxt((size_t)(N_NODES + 1) * 4);
  int*  fill = (int*)  nxt((size_t)N_NODES * 4);
  int*  esrc = (int*)  nxt((size_t)E_EDGES * 4);

  // CSR by dst
  hipMemsetAsync(cnt, 0, (size_t)N_NODES * 4, stream);
  hist_k   <<<(E_EDGES + 255) / 256, 256, 0, stream>>>(ei, cnt);
  scan_k   <<<1, 1024, 0, stream>>>(cnt, rowp, fill, N_NODES);
  scatter_k<<<(E_EDGES + 255) / 256, 256, 0, stream>>>(ei, fill, esrc);

  // weights -> K-major bf16 [Wgat | Wlin]
  tcast_all<<<4864, dim3(32, 8), 0, stream>>>(W1, lw1, Wt1, W2, lw2, Wt2, W3, lw3, Wt3);

  // x -> bf16 padded; zero pad rows of the 1024-wide layout
  castx_k<<<M_PAD, 256, 0, stream>>>(x, Xb, N_NODES);
  zpad_k <<<(96 * 1024 + 255) / 256, 256, 0, stream>>>(Xb + (size_t)N_NODES * 1024, 96 * 1024);

  const int MT = M_PAD / 128;   // 157

  // ---- layer 1 ----
  gemm_bf16<<<dim3(2048 / 256, MT), 256, 0, stream>>>(Xb, Wt1, HG, 2048, 512,  as1, ad1, aS, aD, 4);
  agg4w_k  <<<N_NODES / 4, 256, 0, stream>>>(HG, 2048, rowp, esrc, aS, aD, b1, lb1, Xb);

  // ---- layer 2 ----
  gemm_bf16<<<dim3(2048 / 256, MT), 256, 0, stream>>>(Xb, Wt2, HG, 2048, 1024, as2, ad2, aS, aD, 4);
  agg4w_k  <<<N_NODES / 4, 256, 0, stream>>>(HG, 2048, rowp, esrc, aS, aD, b2, lb2, Xb);

  // ---- layer 3 ----
  gemm_bf16<<<dim3(1792 / 256, MT), 256, 0, stream>>>(Xb, Wt3, HG, 1792, 1024, as3, ad3, aS, aD, 6);
  int outRows = out_size / 256;   // 16384
  agg6w_k  <<<outRows / 4, 256, 0, stream>>>(HG, 1792, rowp, esrc, aS, aD, b3, lb3, (float*)d_out);

  (void)in_sizes; (void)n_in; (void)ws_size;
}

// Round 6
// 804.166 us; speedup vs baseline: 1.1965x; 1.0456x over previous
//
#include <hip/hip_runtime.h>

// ---------------- constants (problem-fixed sizes) ----------------
#define N_NODES 20000
#define M_PAD   20096   // 157 * 128
#define E_EDGES 320000

typedef unsigned short u16;
typedef unsigned int   u32;
typedef __attribute__((ext_vector_type(8))) short bf16x8;
typedef __attribute__((ext_vector_type(4))) float f32x4;
typedef __attribute__((ext_vector_type(4))) u32   u32x4;

__device__ __forceinline__ float bf2f(u16 u){
  u32 x = ((u32)u) << 16; float f; __builtin_memcpy(&f, &x, 4); return f;
}
__device__ __forceinline__ u16 f2bf(float f){
  u32 u; __builtin_memcpy(&u, &f, 4);
  u += 0x7fffu + ((u >> 16) & 1u);          // RNE
  return (u16)(u >> 16);
}
__device__ __forceinline__ float lrelu(float x){ return x > 0.f ? x : 0.2f * x; }

__device__ __forceinline__ void gl_lds16(const void* g, void* l){
  __builtin_amdgcn_global_load_lds((const __attribute__((address_space(1))) void*)g,
                                   (__attribute__((address_space(3))) void*)l, 16, 0, 0);
}

__device__ __forceinline__ void acc8(float* acc, float w, u32x4 p){
#pragma unroll
  for (int d = 0; d < 4; d++){
    u32 u = p[d];
    acc[2 * d]     += w * bf2f((u16)(u & 0xffff));
    acc[2 * d + 1] += w * bf2f((u16)(u >> 16));
  }
}

// ---------------- CSR build ----------------
__global__ void hist_k(const int* __restrict__ ei, int* __restrict__ cnt){
  int i = blockIdx.x * 256 + threadIdx.x;
  if (i < E_EDGES) atomicAdd(&cnt[ei[E_EDGES + i]], 1);
}

// single-block wave-shuffle scan; also writes the fill[] working copy
__global__ void scan_k(const int* __restrict__ cnt, int* __restrict__ rowp,
                       int* __restrict__ fill, int n){
  __shared__ int wsum[16], wpre[16];
  __shared__ int carry;
  int tid = threadIdx.x, lane = tid & 63, wv = tid >> 6;
  if (tid == 0) carry = 0;
  __syncthreads();
  for (int base = 0; base < n; base += 1024){
    int i = base + tid;
    int v = (i < n) ? cnt[i] : 0;
    int incl = v;
#pragma unroll
    for (int d = 1; d < 64; d <<= 1){
      int t = __shfl_up(incl, d, 64);
      if (lane >= d) incl += t;
    }
    if (lane == 63) wsum[wv] = incl;
    __syncthreads();
    if (tid == 0){
      int s = carry;
#pragma unroll
      for (int w = 0; w < 16; w++){ wpre[w] = s; s += wsum[w]; }
      carry = s;
    }
    __syncthreads();
    if (i < n){ int e = wpre[wv] + incl - v; rowp[i] = e; fill[i] = e; }
  }
  __syncthreads();
  if (tid == 0) rowp[n] = carry;
}

__global__ void scatter_k(const int* __restrict__ ei, int* __restrict__ fill, int* __restrict__ esrc){
  int i = blockIdx.x * 256 + threadIdx.x;
  if (i < E_EDGES){
    int d = ei[E_EDGES + i];
    int p = atomicAdd(&fill[d], 1);
    esrc[p] = ei[i];
  }
}

// ---------------- weight transpose+cast, all 6 jobs in one kernel ----------------
__global__ void tcast_all(const float* __restrict__ W1, const float* __restrict__ lw1, u16* __restrict__ Wt1,
                          const float* __restrict__ W2, const float* __restrict__ lw2, u16* __restrict__ Wt2,
                          const float* __restrict__ W3, const float* __restrict__ lw3, u16* __restrict__ Wt3)
{
  __shared__ float tile[32][33];
  int b = blockIdx.x;
  const float* src; u16* dst; int Nc, n0, ldd;
  if      (b <  512){            src = W1;  Nc = 1024; dst = Wt1; n0 = 0;    ldd = 512;  }
  else if (b < 1024){ b -=  512; src = lw1; Nc = 1024; dst = Wt1; n0 = 1024; ldd = 512;  }
  else if (b < 2048){ b -= 1024; src = W2;  Nc = 1024; dst = Wt2; n0 = 0;    ldd = 1024; }
  else if (b < 3072){ b -= 2048; src = lw2; Nc = 1024; dst = Wt2; n0 = 1024; ldd = 1024; }
  else if (b < 4608){ b -= 3072; src = W3;  Nc = 1536; dst = Wt3; n0 = 0;    ldd = 1024; }
  else              { b -= 4608; src = lw3; Nc = 256;  dst = Wt3; n0 = 1536; ldd = 1024; }
  int gx = Nc / 32;
  int kb = (b / gx) * 32, nb = (b % gx) * 32;
  int tx = threadIdx.x, ty = threadIdx.y;
#pragma unroll
  for (int r = 0; r < 32; r += 8)
    tile[ty + r][tx] = src[(size_t)(kb + ty + r) * Nc + nb + tx];
  __syncthreads();
#pragma unroll
  for (int r = 0; r < 32; r += 8){
    int n = nb + ty + r;
    dst[(size_t)(n0 + n) * ldd + kb + tx] = f2bf(tile[tx][ty + r]);
  }
}

// one row per block, 512 cols, float2 -> packed 2xbf16
__global__ void castx_k(const float* __restrict__ x, u16* __restrict__ o, int realRows){
  int r = blockIdx.x, c = threadIdx.x * 2;
  float2 v = (r < realRows) ? *(const float2*)(x + (size_t)r * 512 + c) : make_float2(0.f, 0.f);
  u32 pk = ((u32)f2bf(v.y) << 16) | (u32)f2bf(v.x);
  *(u32*)(o + (size_t)r * 512 + c) = pk;
}

__global__ void zpad_k(u16* __restrict__ p, int n){
  int i = blockIdx.x * 256 + threadIdx.x; if (i < n) p[i] = 0;
}

// ---------------- bf16 NT GEMM + fused alpha epilogue, DOUBLE-BUFFERED ----------------
// C[M][N] = A[M][K] * Bt[N][K]^T ; 128x256 tile, BK=32, 256 threads.
// LDS 2x24KB; one barrier per K-iter: drains loads issued a full iter earlier,
// then immediately issues next-iter loads into the other buffer.
__global__ __launch_bounds__(256, 2)
void gemm_bf16(const u16* __restrict__ A, const u16* __restrict__ Bt, u16* __restrict__ C,
               int N, int K,
               const float* __restrict__ a_s, const float* __restrict__ a_d,
               float* __restrict__ aS, float* __restrict__ aD, int H)
{
  __shared__ __attribute__((aligned(16))) u16 lAB[2][12288];  // 2 x (8KB A + 16KB B)
  const int tid  = threadIdx.x;
  const int wave = tid >> 6, lane = tid & 63;
  const int bn = blockIdx.x, bm = blockIdx.y;
  const int wm = (wave >> 1) * 64, wn = (wave & 1) * 128;

  const int srow  = wave * 16 + (lane >> 2);
  const int skcol = (lane & 3) * 8;
  const u16* Ag0 = A  + (size_t)(bm * 128 + srow) * K + skcol;
  const u16* Ag1 = Ag0 + (size_t)64 * K;
  const u16* Bg  = Bt + (size_t)(bn * 256 + srow) * K + skcol;
  const int woff = wave * 512;

  f32x4 acc[4][8] = {};

  // prologue: stage tile 0 into buffer 0
  {
    u16* a0 = &lAB[0][woff];
    u16* a1 = &lAB[0][2048 + woff];
    u16* bw = &lAB[0][4096 + woff];
    gl_lds16(Ag0, a0);
    gl_lds16(Ag1, a1);
#pragma unroll
    for (int c = 0; c < 4; c++)
      gl_lds16(Bg + (size_t)(c * 64) * K, bw + c * 2048);
  }

  for (int k0 = 0; k0 < K; k0 += 32){
    const int p = (k0 >> 5) & 1;
    __syncthreads();                        // tile(k0) loads done; buf p^1 free (WAR)
    if (k0 + 32 < K){                       // prefetch next tile into other buffer
      u16* a0 = &lAB[p ^ 1][woff];
      u16* a1 = &lAB[p ^ 1][2048 + woff];
      u16* bw = &lAB[p ^ 1][4096 + woff];
      gl_lds16(Ag0 + k0 + 32, a0);
      gl_lds16(Ag1 + k0 + 32, a1);
#pragma unroll
      for (int c = 0; c < 4; c++)
        gl_lds16(Bg + (size_t)(c * 64) * K + k0 + 32, bw + c * 2048);
    }
    const u16* lA = &lAB[p][0];
    const u16* lB = &lAB[p][4096];
    const int koff = (lane >> 4) * 8;
    const int rsel = lane & 15;
    bf16x8 af[4], bfr[8];
#pragma unroll
    for (int i = 0; i < 4; i++) af[i]  = *(const bf16x8*)&lA[(wm + i * 16 + rsel) * 32 + koff];
#pragma unroll
    for (int j = 0; j < 8; j++) bfr[j] = *(const bf16x8*)&lB[(wn + j * 16 + rsel) * 32 + koff];
#pragma unroll
    for (int i = 0; i < 4; i++)
#pragma unroll
      for (int j = 0; j < 8; j++)
        acc[i][j] = __builtin_amdgcn_mfma_f32_16x16x32_bf16(af[i], bfr[j], acc[i][j], 0, 0, 0);
  }

  const int r0 = (lane >> 4) * 4, cl = lane & 15;
#pragma unroll
  for (int i = 0; i < 4; i++)
#pragma unroll
    for (int j = 0; j < 8; j++){
      int row = bm * 128 + wm + i * 16 + r0;
      int col = bn * 256 + wn + j * 16 + cl;
      u16* cp = C + (size_t)row * N + col;
#pragma unroll
      for (int r = 0; r < 4; r++) cp[(size_t)r * N] = f2bf(acc[i][j][r]);
    }

  // ---- fused alpha: aS/aD[row*8 + bn] for gat heads ----
  if (bn < H){
    __syncthreads();                        // all waves done reading LDS tiles
    float* fa = (float*)&lAB[0][0];         // [0..255]=a_s, [256..511]=a_d
    fa[tid]       = a_s[bn * 256 + tid];
    fa[256 + tid] = a_d[bn * 256 + tid];
    __syncthreads();
    float* fb = (float*)&lAB[1][0];         // parts: s [0..255], d [256..511]
    const int q = lane >> 4;
#pragma unroll
    for (int i = 0; i < 4; i++)
#pragma unroll
      for (int r = 0; r < 4; r++){
        float ps = 0.f, pd = 0.f;
#pragma unroll
        for (int j = 0; j < 8; j++){
          float v = acc[i][j][r];
          int c = wn + j * 16 + cl;
          ps += v * fa[c];
          pd += v * fa[256 + c];
        }
#pragma unroll
        for (int m = 1; m < 16; m <<= 1){
          ps += __shfl_xor(ps, m, 64);
          pd += __shfl_xor(pd, m, 64);
        }
        if (cl == 0){
          int row = wm + i * 16 + q * 4 + r;
          fb[(wave & 1) * 128 + row]       = ps;
          fb[256 + (wave & 1) * 128 + row] = pd;
        }
      }
    __syncthreads();
    if (tid < 128){
      int row = bm * 128 + tid;
      aS[(size_t)row * 8 + bn] = fb[tid] + fb[128 + tid];
      aD[(size_t)row * 8 + bn] = fb[256 + tid] + fb[384 + tid];
    }
  }
}

// ---------------- H=4 wave-per-dst softmax+aggregate ----------------
// 256 threads = 4 waves = 4 dst. Lane i owns edge i (deg<=63 fast path).
__global__ __launch_bounds__(256)
void agg4w_k(const u16* __restrict__ HG, int ldH,
             const int* __restrict__ rowp, const int* __restrict__ esrc,
             const float* __restrict__ aS, const float* __restrict__ aD,
             const float* __restrict__ bias, const float* __restrict__ lbias,
             u16* __restrict__ outb)
{
  __shared__ float s_w[4][256];             // [wave][edge*4+h], normalized weights
  const int tid = threadIdx.x, lane = tid & 63, wv = tid >> 6;
  const int dst = blockIdx.x * 4 + wv;      // grid*4 == 20000 exactly
  const int e0 = rowp[dst];
  const int deg = rowp[dst + 1] - e0;
  const int nE = deg + 1;                   // + implicit self loop (index == deg)
  const float4 adv = *(const float4*)(aD + (size_t)dst * 8);

  // ---- P1: per-lane edge logits + wave max ----
  int myS = dst;
  float ea = -1e30f, eb = -1e30f, ec = -1e30f, ed = -1e30f;
  if (lane < nE){
    myS = (lane == deg) ? dst : esrc[e0 + lane];
    float4 as = *(const float4*)(aS + (size_t)myS * 8);
    ea = lrelu(as.x + adv.x); eb = lrelu(as.y + adv.y);
    ec = lrelu(as.z + adv.z); ed = lrelu(as.w + adv.w);
  }
  float m0 = ea, m1 = eb, m2 = ec, m3 = ed;
  for (int i = lane + 64; i < nE; i += 64){
    int s = (i == deg) ? dst : esrc[e0 + i];
    float4 as = *(const float4*)(aS + (size_t)s * 8);
    m0 = fmaxf(m0, lrelu(as.x + adv.x)); m1 = fmaxf(m1, lrelu(as.y + adv.y));
    m2 = fmaxf(m2, lrelu(as.z + adv.z)); m3 = fmaxf(m3, lrelu(as.w + adv.w));
  }
#pragma unroll
  for (int off = 1; off < 64; off <<= 1){
    m0 = fmaxf(m0, __shfl_xor(m0, off)); m1 = fmaxf(m1, __shfl_xor(m1, off));
    m2 = fmaxf(m2, __shfl_xor(m2, off)); m3 = fmaxf(m3, __shfl_xor(m3, off));
  }

  // ---- P2: exp + wave sum (invalid lanes give exp(-huge)=0) ----
  float w0 = __expf(ea - m0), w1 = __expf(eb - m1);
  float w2 = __expf(ec - m2), w3 = __expf(ed - m3);
  float l0 = w0, l1 = w1, l2 = w2, l3 = w3;
  for (int i = lane + 64; i < nE; i += 64){
    int s = (i == deg) ? dst : esrc[e0 + i];
    float4 as = *(const float4*)(aS + (size_t)s * 8);
    l0 += __expf(lrelu(as.x + adv.x) - m0); l1 += __expf(lrelu(as.y + adv.y) - m1);
    l2 += __expf(lrelu(as.z + adv.z) - m2); l3 += __expf(lrelu(as.w + adv.w) - m3);
  }
#pragma unroll
  for (int off = 1; off < 64; off <<= 1){
    l0 += __shfl_xor(l0, off); l1 += __shfl_xor(l1, off);
    l2 += __shfl_xor(l2, off); l3 += __shfl_xor(l3, off);
  }
  float d0 = 1.f / (l0 + 1e-16f), d1 = 1.f / (l1 + 1e-16f);
  float d2 = 1.f / (l2 + 1e-16f), d3 = 1.f / (l3 + 1e-16f);
  *(float4*)&s_w[wv][lane * 4] = make_float4(w0 * d0, w1 * d1, w2 * d2, w3 * d3);
  __syncthreads();

  // ---- P3: full-row weighted gather, 16 ch (32B) per lane, 4-edge unroll ----
  const int h = lane >> 4;                  // single head per lane (16 | 256)
  const int ch0 = lane * 16;
  const float mh   = (h < 2) ? (h == 0 ? m0 : m1) : (h == 2 ? m2 : m3);
  const float dh   = (h < 2) ? (h == 0 ? d0 : d1) : (h == 2 ? d2 : d3);
  const float advh = (h < 2) ? (h == 0 ? adv.x : adv.y) : (h == 2 ? adv.z : adv.w);
  float acc[16] = {};
  const u16* HGc = HG + ch0;
  const int nF = nE < 64 ? nE : 64;
  int i = 0;
  for (; i + 3 < nF; i += 4){
    int sA = __shfl(myS, i),     sB = __shfl(myS, i + 1);
    int sC = __shfl(myS, i + 2), sD = __shfl(myS, i + 3);
    float wA = s_w[wv][i * 4 + h],       wB = s_w[wv][(i + 1) * 4 + h];
    float wC = s_w[wv][(i + 2) * 4 + h], wD = s_w[wv][(i + 3) * 4 + h];
    const u16* ra = HGc + (size_t)sA * ldH;
    const u16* rb = HGc + (size_t)sB * ldH;
    const u16* rc = HGc + (size_t)sC * ldH;
    const u16* rd = HGc + (size_t)sD * ldH;
    u32x4 pa0 = *(const u32x4*)ra, pa1 = *(const u32x4*)(ra + 8);
    u32x4 pb0 = *(const u32x4*)rb, pb1 = *(const u32x4*)(rb + 8);
    u32x4 pc0 = *(const u32x4*)rc, pc1 = *(const u32x4*)(rc + 8);
    u32x4 pd0 = *(const u32x4*)rd, pd1 = *(const u32x4*)(rd + 8);
    acc8(acc, wA, pa0); acc8(acc + 8, wA, pa1);
    acc8(acc, wB, pb0); acc8(acc + 8, wB, pb1);
    acc8(acc, wC, pc0); acc8(acc + 8, wC, pc1);
    acc8(acc, wD, pd0); acc8(acc + 8, wD, pd1);
  }
  for (; i < nF; i++){
    int sA = __shfl(myS, i);
    float wA = s_w[wv][i * 4 + h];
    const u16* ra = HGc + (size_t)sA * ldH;
    acc8(acc, wA, *(const u32x4*)ra); acc8(acc + 8, wA, *(const u32x4*)(ra + 8));
  }
  for (int j = 64; j < nE; j++){            // rare high-degree tail
    int s = (j == deg) ? dst : esrc[e0 + j];
    float e = lrelu(aS[(size_t)s * 8 + h] + advh);
    float w = __expf(e - mh) * dh;
    const u16* r = HGc + (size_t)s * ldH;
    acc8(acc, w, *(const u32x4*)r); acc8(acc + 8, w, *(const u32x4*)(r + 8));
  }

  // ---- epilogue: +bias +linear +ELU -> next-layer bf16 input ----
  const u16* lr = HG + (size_t)dst * ldH + 1024 + ch0;
  u32x4 q0 = *(const u32x4*)lr, q1 = *(const u32x4*)(lr + 8);
  float lin[16];
#pragma unroll
  for (int d = 0; d < 4; d++){
    lin[2*d]     = bf2f((u16)(q0[d] & 0xffff)); lin[2*d+1]   = bf2f((u16)(q0[d] >> 16));
    lin[8+2*d]   = bf2f((u16)(q1[d] & 0xffff)); lin[8+2*d+1] = bf2f((u16)(q1[d] >> 16));
  }
  u32 o[8];
#pragma unroll
  for (int d = 0; d < 8; d++){
    float va = acc[2*d]   + bias[ch0 + 2*d]   + lin[2*d]   + lbias[ch0 + 2*d];
    float vb = acc[2*d+1] + bias[ch0 + 2*d+1] + lin[2*d+1] + lbias[ch0 + 2*d+1];
    va = va > 0.f ? va : __expf(va) - 1.f;
    vb = vb > 0.f ? vb : __expf(vb) - 1.f;
    o[d] = ((u32)f2bf(vb) << 16) | (u32)f2bf(va);
  }
  u16* op = outb + (size_t)dst * 1024 + ch0;
  *(u32x4*)op = *(u32x4*)o;
  *(u32x4*)(op + 8) = *(u32x4*)(o + 4);
}

// ---------------- H=6 FINAL wave-per-dst, head-mean folded into weights ----------------
// Half-wave = edge parity; lane owns 8 OUTPUT channels; acc = sum_h (w/6)*H.
__global__ __launch_bounds__(256)
void agg6w_k(const u16* __restrict__ HG, int ldH,
             const int* __restrict__ rowp, const int* __restrict__ esrc,
             const float* __restrict__ aS, const float* __restrict__ aD,
             const float* __restrict__ bias, const float* __restrict__ lbias,
             float* __restrict__ outf)
{
  __shared__ float s_w[4][64 * 6];          // 6 KB: w_norm/6 per edge x head
  const int tid = threadIdx.x, lane = tid & 63, wv = tid >> 6;
  const int dst = blockIdx.x * 4 + wv;      // grid*4 == 16384 exactly
  const int e0 = rowp[dst];
  const int deg = rowp[dst + 1] - e0;
  const int nE = deg + 1;

  const float* advp = aD + (size_t)dst * 8;
  float4 av4 = *(const float4*)advp; float2 av2 = *(const float2*)(advp + 4);
  float adv[6] = { av4.x, av4.y, av4.z, av4.w, av2.x, av2.y };

  // ---- P1: per-lane logits + wave max ----
  int myS = dst;
  float e[6];
#pragma unroll
  for (int h = 0; h < 6; h++) e[h] = -1e30f;
  if (lane < nE){
    myS = (lane == deg) ? dst : esrc[e0 + lane];
    float4 a0 = *(const float4*)(aS + (size_t)myS * 8);
    float2 a1 = *(const float2*)(aS + (size_t)myS * 8 + 4);
    e[0] = lrelu(a0.x + adv[0]); e[1] = lrelu(a0.y + adv[1]);
    e[2] = lrelu(a0.z + adv[2]); e[3] = lrelu(a0.w + adv[3]);
    e[4] = lrelu(a1.x + adv[4]); e[5] = lrelu(a1.y + adv[5]);
  }
  float m[6];
#pragma unroll
  for (int h = 0; h < 6; h++) m[h] = e[h];
  for (int i = lane + 64; i < nE; i += 64){
    int s = (i == deg) ? dst : esrc[e0 + i];
    float4 a0 = *(const float4*)(aS + (size_t)s * 8);
    float2 a1 = *(const float2*)(aS + (size_t)s * 8 + 4);
    float t[6] = { a0.x, a0.y, a0.z, a0.w, a1.x, a1.y };
#pragma unroll
    for (int h = 0; h < 6; h++) m[h] = fmaxf(m[h], lrelu(t[h] + adv[h]));
  }
#pragma unroll
  for (int h = 0; h < 6; h++)
#pragma unroll
    for (int off = 1; off < 64; off <<= 1) m[h] = fmaxf(m[h], __shfl_xor(m[h], off));

  // ---- P2: exp + wave sum; store w_norm * (1/6) ----
  float w[6], l[6];
#pragma unroll
  for (int h = 0; h < 6; h++){ w[h] = __expf(e[h] - m[h]); l[h] = w[h]; }
  for (int i = lane + 64; i < nE; i += 64){
    int s = (i == deg) ? dst : esrc[e0 + i];
    float4 a0 = *(const float4*)(aS + (size_t)s * 8);
    float2 a1 = *(const float2*)(aS + (size_t)s * 8 + 4);
    float t[6] = { a0.x, a0.y, a0.z, a0.w, a1.x, a1.y };
#pragma unroll
    for (int h = 0; h < 6; h++) l[h] += __expf(lrelu(t[h] + adv[h]) - m[h]);
  }
#pragma unroll
  for (int h = 0; h < 6; h++)
#pragma unroll
    for (int off = 1; off < 64; off <<= 1) l[h] += __shfl_xor(l[h], off);
  float dv[6];
#pragma unroll
  for (int h = 0; h < 6; h++) dv[h] = (1.f / 6.f) / (l[h] + 1e-16f);
  float* swp = &s_w[wv][lane * 6];
  ((float2*)swp)[0] = make_float2(w[0] * dv[0], w[1] * dv[1]);
  ((float2*)swp)[1] = make_float2(w[2] * dv[2], w[3] * dv[3]);
  ((float2*)swp)[2] = make_float2(w[4] * dv[4], w[5] * dv[5]);
  __syncthreads();

  // ---- P3: half-wave edge parity, 8 output ch/lane, 6 heads x dwordx4 ----
  const int li = lane & 31, half = lane >> 5;
  const int ch0 = li * 8;
  float acc[8] = {};
  const u16* HGc = HG + ch0;
  const int nF = nE < 64 ? nE : 64;
  for (int i = half; i < nF; i += 2){       // weights are 0 for i >= nE
    int s = __shfl(myS, i);
    const u16* r = HGc + (size_t)s * ldH;
    const float* wp6 = &s_w[wv][i * 6];
#pragma unroll
    for (int h = 0; h < 6; h++){
      u32x4 p = *(const u32x4*)(r + h * 256);
      acc8(acc, wp6[h], p);
    }
  }
  for (int j = 64 + half; j < nE; j += 2){  // rare high-degree tail
    int s = (j == deg) ? dst : esrc[e0 + j];
    float4 a0 = *(const float4*)(aS + (size_t)s * 8);
    float2 a1 = *(const float2*)(aS + (size_t)s * 8 + 4);
    float t[6] = { a0.x, a0.y, a0.z, a0.w, a1.x, a1.y };
    const u16* r = HGc + (size_t)s * ldH;
#pragma unroll
    for (int h = 0; h < 6; h++){
      float wt = __expf(lrelu(t[h] + adv[h]) - m[h]) * dv[h];
      u32x4 p = *(const u32x4*)(r + h * 256);
      acc8(acc, wt, p);
    }
  }
#pragma unroll
  for (int c = 0; c < 8; c++) acc[c] += __shfl_xor(acc[c], 32);

  // ---- epilogue (lanes 0..31): + bias + linear + lbias, f32 out ----
  if (lane < 32){
    u32x4 q = *(const u32x4*)(HG + (size_t)dst * ldH + 1536 + ch0);
    float lin[8];
#pragma unroll
    for (int d = 0; d < 4; d++){
      lin[2*d]   = bf2f((u16)(q[d] & 0xffff));
      lin[2*d+1] = bf2f((u16)(q[d] >> 16));
    }
    float4 b0 = *(const float4*)(bias + ch0),  b1 = *(const float4*)(bias + ch0 + 4);
    float4 c0 = *(const float4*)(lbias + ch0), c1 = *(const float4*)(lbias + ch0 + 4);
    float4 o0, o1;
    o0.x = acc[0] + b0.x + lin[0] + c0.x; o0.y = acc[1] + b0.y + lin[1] + c0.y;
    o0.z = acc[2] + b0.z + lin[2] + c0.z; o0.w = acc[3] + b0.w + lin[3] + c0.w;
    o1.x = acc[4] + b1.x + lin[4] + c1.x; o1.y = acc[5] + b1.y + lin[5] + c1.y;
    o1.z = acc[6] + b1.z + lin[6] + c1.z; o1.w = acc[7] + b1.w + lin[7] + c1.w;
    float* op = outf + (size_t)dst * 256 + ch0;
    *(float4*)op = o0;
    *(float4*)(op + 4) = o1;
  }
}

// ---------------- host orchestration ----------------
extern "C" void kernel_launch(void* const* d_in, const int* in_sizes, int n_in,
                              void* d_out, int out_size, void* d_ws, size_t ws_size,
                              hipStream_t stream)
{
  const float* x   = (const float*)d_in[0];
  const int*   ei  = (const int*)  d_in[1];
  const float* W1  = (const float*)d_in[3];
  const float* as1 = (const float*)d_in[4];
  const float* ad1 = (const float*)d_in[5];
  const float* b1  = (const float*)d_in[6];
  const float* lw1 = (const float*)d_in[7];
  const float* lb1 = (const float*)d_in[8];
  const float* W2  = (const float*)d_in[9];
  const float* as2 = (const float*)d_in[10];
  const float* ad2 = (const float*)d_in[11];
  const float* b2  = (const float*)d_in[12];
  const float* lw2 = (const float*)d_in[13];
  const float* lb2 = (const float*)d_in[14];
  const float* W3  = (const float*)d_in[15];
  const float* as3 = (const float*)d_in[16];
  const float* ad3 = (const float*)d_in[17];
  const float* b3  = (const float*)d_in[18];
  const float* lw3 = (const float*)d_in[19];
  const float* lb3 = (const float*)d_in[20];

  char* wp = (char*)d_ws;
  auto nxt = [&](size_t b) -> void* {
    void* p = (void*)wp; wp += (b + 255) & ~(size_t)255; return p;
  };
  u16*  Wt1  = (u16*) nxt((size_t)2048 * 512  * 2);
  u16*  Wt2  = (u16*) nxt((size_t)2048 * 1024 * 2);
  u16*  Wt3  = (u16*) nxt((size_t)1792 * 1024 * 2);
  u16*  Xb   = (u16*) nxt((size_t)M_PAD * 1024 * 2);
  u16*  HG   = (u16*) nxt((size_t)M_PAD * 2048 * 2);
  float* aS  = (float*)nxt((size_t)M_PAD * 8 * 4);
  float* aD  = (float*)nxt((size_t)M_PAD * 8 * 4);
  int*  cnt  = (int*)  nxt((size_t)N_NODES * 4);
  int*  rowp = (int*)  nxt((size_t)(N_NODES + 1) * 4);
  int*  fill = (int*)  nxt((size_t)N_NODES * 4);
  int*  esrc = (int*)  nxt((size_t)E_EDGES * 4);

  // CSR by dst
  hipMemsetAsync(cnt, 0, (size_t)N_NODES * 4, stream);
  hist_k   <<<(E_EDGES + 255) / 256, 256, 0, stream>>>(ei, cnt);
  scan_k   <<<1, 1024, 0, stream>>>(cnt, rowp, fill, N_NODES);
  scatter_k<<<(E_EDGES + 255) / 256, 256, 0, stream>>>(ei, fill, esrc);

  // weights -> K-major bf16 [Wgat | Wlin]
  tcast_all<<<4864, dim3(32, 8), 0, stream>>>(W1, lw1, Wt1, W2, lw2, Wt2, W3, lw3, Wt3);

  // x -> bf16 padded; zero pad rows of the 1024-wide layout
  castx_k<<<M_PAD, 256, 0, stream>>>(x, Xb, N_NODES);
  zpad_k <<<(96 * 1024 + 255) / 256, 256, 0, stream>>>(Xb + (size_t)N_NODES * 1024, 96 * 1024);

  const int MT = M_PAD / 128;   // 157

  // ---- layer 1 ----
  gemm_bf16<<<dim3(2048 / 256, MT), 256, 0, stream>>>(Xb, Wt1, HG, 2048, 512,  as1, ad1, aS, aD, 4);
  agg4w_k  <<<N_NODES / 4, 256, 0, stream>>>(HG, 2048, rowp, esrc, aS, aD, b1, lb1, Xb);

  // ---- layer 2 ----
  gemm_bf16<<<dim3(2048 / 256, MT), 256, 0, stream>>>(Xb, Wt2, HG, 2048, 1024, as2, ad2, aS, aD, 4);
  agg4w_k  <<<N_NODES / 4, 256, 0, stream>>>(HG, 2048, rowp, esrc, aS, aD, b2, lb2, Xb);

  // ---- layer 3 ----
  gemm_bf16<<<dim3(1792 / 256, MT), 256, 0, stream>>>(Xb, Wt3, HG, 1792, 1024, as3, ad3, aS, aD, 6);
  int outRows = out_size / 256;   // 16384
  agg6w_k  <<<outRows / 4, 256, 0, stream>>>(HG, 1792, rowp, esrc, aS, aD, b3, lb3, (float*)d_out);

  (void)in_sizes; (void)n_in; (void)ws_size;
}